// Round 1
// baseline (1555.694 us; speedup 1.0000x reference)
//
#include <hip/hip_runtime.h>

#define NN 100000
#define DD 128
#define EE 500000
#define RR 3

// ---------------- precompute fused weights ----------------
// QB layout: [4][128][128]; seg 0 = Qx = sum_r Wr_r @ P1_r, seg 1..3 = Q_r = Wl_r @ P1_r
__global__ __launch_bounds__(128) void precompute_qb_kernel(
    const float* __restrict__ Wl, const float* __restrict__ Wr,
    const float* __restrict__ P1, float* __restrict__ QB)
{
    int s = blockIdx.x >> 7;   // 0..3
    int i = blockIdx.x & 127;  // row
    int j = threadIdx.x;       // col
    float acc = 0.f;
    if (s == 0) {
        for (int r = 0; r < RR; ++r) {
            const float* wrow = Wr + (size_t)(r * DD + i) * DD;
            const float* pcol = P1 + (size_t)(r * DD) * DD + j;
            for (int k = 0; k < DD; ++k)
                acc += wrow[k] * pcol[(size_t)k * DD];
        }
    } else {
        int r = s - 1;
        const float* wrow = Wl + (size_t)(r * DD + i) * DD;
        const float* pcol = P1 + (size_t)(r * DD) * DD + j;
        for (int k = 0; k < DD; ++k)
            acc += wrow[k] * pcol[(size_t)k * DD];
    }
    QB[(size_t)(s * DD + i) * DD + j] = acc;
}

__global__ __launch_bounds__(128) void precompute_c_kernel(
    const float* __restrict__ bl, const float* __restrict__ P1,
    const float* __restrict__ b1, float* __restrict__ cb)
{
    int j = threadIdx.x;
    float acc = b1[j];
    for (int r = 0; r < RR; ++r)
        for (int k = 0; k < DD; ++k)
            acc += bl[r * DD + k] * P1[(size_t)(r * DD + k) * DD + j];
    cb[j] = acc;
}

// ---------------- edge scatter: one wave64 per edge ----------------
__global__ __launch_bounds__(256) void scatter_kernel(
    const int* __restrict__ e0, const int* __restrict__ e1, const int* __restrict__ e2,
    const float* __restrict__ x, float* __restrict__ agg, int* __restrict__ cnt)
{
    int gw = blockIdx.x * 4 + (threadIdx.x >> 6);  // global edge id, < 3E (grid exact)
    int lane = threadIdx.x & 63;
    int r = gw / EE;
    int e = gw - r * EE;
    const int* ei = (r == 0) ? e0 : (r == 1) ? e1 : e2;
    int src = ei[e];
    int dst = ei[EE + e];
    float2 v = ((const float2*)(x + (size_t)src * DD))[lane];
    float* a = agg + ((size_t)r * NN + dst) * DD + lane * 2;
    atomicAdd(a, v.x);
    atomicAdd(a + 1, v.y);
    if (lane == 0) atomicAdd(cnt + r * NN + dst, 1);
}

__global__ __launch_bounds__(256) void inv_kernel(
    const int* __restrict__ cnt, float* __restrict__ inv)
{
    int i = blockIdx.x * 256 + threadIdx.x;
    if (i < RR * NN) {
        int c = cnt[i];
        inv[i] = 1.0f / (float)(c > 1 ? c : 1);
    }
}

// ---------------- GEMM1: h = relu([x|agg0/c|agg1/c|agg2/c] @ QB + cb) ----------------
// 64 rows/block, K-chunks of 64, 8x4 micro-tile per thread (256 threads).
__global__ __launch_bounds__(256) void gemm1_kernel(
    const float* __restrict__ x, const float* __restrict__ agg,
    const float* __restrict__ inv, const float* __restrict__ QB,
    const float* __restrict__ cb, float* __restrict__ h)
{
    __shared__ float As[64][68];      // [k][row], padded
    __shared__ float Bs[64 * 128];    // [k][j]
    int tid = threadIdx.x;
    int n0 = blockIdx.x * 64;
    int col_t = tid & 31;             // cols col_t*4 .. +3
    int row_t = tid >> 5;             // rows row_t*8 .. +7

    float acc[8][4];
    #pragma unroll
    for (int i = 0; i < 8; ++i)
        #pragma unroll
        for (int j = 0; j < 4; ++j) acc[i][j] = 0.f;

    int lrow = tid >> 2;              // 0..63  (A-load row)
    int lkq  = (tid & 3) * 16;        // k offset within chunk

    for (int chunk = 0; chunk < 8; ++chunk) {
        int seg = chunk >> 1;
        int k0 = (chunk & 1) * 64;
        const float* Aseg = (seg == 0) ? (x + (size_t)n0 * DD)
                                       : (agg + ((size_t)(seg - 1) * NN + n0) * DD);
        int grow = n0 + lrow;
        bool rok = grow < NN;
        float scale = 0.0f;
        if (rok) scale = (seg == 0) ? 1.0f : inv[(seg - 1) * NN + grow];

        #pragma unroll
        for (int i = 0; i < 4; ++i) {
            float4 v = make_float4(0.f, 0.f, 0.f, 0.f);
            if (rok) v = *(const float4*)(Aseg + (size_t)lrow * DD + k0 + lkq + i * 4);
            int kk = lkq + i * 4;
            As[kk + 0][lrow] = v.x * scale;
            As[kk + 1][lrow] = v.y * scale;
            As[kk + 2][lrow] = v.z * scale;
            As[kk + 3][lrow] = v.w * scale;
        }
        const float4* Bsrc = (const float4*)(QB + (size_t)(seg * DD + k0) * DD);
        float4* Bd = (float4*)Bs;
        #pragma unroll
        for (int i = 0; i < 8; ++i)
            Bd[i * 256 + tid] = Bsrc[i * 256 + tid];
        __syncthreads();

        #pragma unroll 4
        for (int kk = 0; kk < 64; ++kk) {
            float4 b = *(const float4*)(Bs + kk * 128 + col_t * 4);
            const float* ap = &As[kk][row_t * 8];
            float4 a0 = *(const float4*)(ap);
            float4 a1 = *(const float4*)(ap + 4);
            float av[8] = {a0.x, a0.y, a0.z, a0.w, a1.x, a1.y, a1.z, a1.w};
            #pragma unroll
            for (int i = 0; i < 8; ++i) {
                acc[i][0] += av[i] * b.x;
                acc[i][1] += av[i] * b.y;
                acc[i][2] += av[i] * b.z;
                acc[i][3] += av[i] * b.w;
            }
        }
        __syncthreads();
    }

    float4 cv = *(const float4*)(cb + col_t * 4);
    #pragma unroll
    for (int i = 0; i < 8; ++i) {
        int row = n0 + row_t * 8 + i;
        if (row < NN) {
            float4 o;
            o.x = acc[i][0] + cv.x;
            o.y = acc[i][1] + cv.y;
            o.z = acc[i][2] + cv.z;
            o.w = acc[i][3] + cv.w;
            o.x = o.x > 0.f ? o.x : 0.f;
            o.y = o.y > 0.f ? o.y : 0.f;
            o.z = o.z > 0.f ? o.z : 0.f;
            o.w = o.w > 0.f ? o.w : 0.f;
            *(float4*)(h + (size_t)row * DD + col_t * 4) = o;
        }
    }
}

// ---------------- GEMM2: out = h @ P2 + b2 (in-place on d_out) ----------------
__global__ __launch_bounds__(256) void gemm2_kernel(
    const float* __restrict__ P2, const float* __restrict__ b2,
    float* __restrict__ out)
{
    __shared__ float As[64][68];
    __shared__ float Bs[64 * 128];
    int tid = threadIdx.x;
    int n0 = blockIdx.x * 64;
    int col_t = tid & 31;
    int row_t = tid >> 5;

    float acc[8][4];
    #pragma unroll
    for (int i = 0; i < 8; ++i)
        #pragma unroll
        for (int j = 0; j < 4; ++j) acc[i][j] = 0.f;

    int lrow = tid >> 2;
    int lkq  = (tid & 3) * 16;

    for (int chunk = 0; chunk < 2; ++chunk) {
        int k0 = chunk * 64;
        int grow = n0 + lrow;
        bool rok = grow < NN;
        #pragma unroll
        for (int i = 0; i < 4; ++i) {
            float4 v = make_float4(0.f, 0.f, 0.f, 0.f);
            if (rok) v = *(const float4*)(out + (size_t)grow * DD + k0 + lkq + i * 4);
            int kk = lkq + i * 4;
            As[kk + 0][lrow] = v.x;
            As[kk + 1][lrow] = v.y;
            As[kk + 2][lrow] = v.z;
            As[kk + 3][lrow] = v.w;
        }
        const float4* Bsrc = (const float4*)(P2 + (size_t)k0 * DD);
        float4* Bd = (float4*)Bs;
        #pragma unroll
        for (int i = 0; i < 8; ++i)
            Bd[i * 256 + tid] = Bsrc[i * 256 + tid];
        __syncthreads();

        #pragma unroll 4
        for (int kk = 0; kk < 64; ++kk) {
            float4 b = *(const float4*)(Bs + kk * 128 + col_t * 4);
            const float* ap = &As[kk][row_t * 8];
            float4 a0 = *(const float4*)(ap);
            float4 a1 = *(const float4*)(ap + 4);
            float av[8] = {a0.x, a0.y, a0.z, a0.w, a1.x, a1.y, a1.z, a1.w};
            #pragma unroll
            for (int i = 0; i < 8; ++i) {
                acc[i][0] += av[i] * b.x;
                acc[i][1] += av[i] * b.y;
                acc[i][2] += av[i] * b.z;
                acc[i][3] += av[i] * b.w;
            }
        }
        __syncthreads();
    }

    float4 bv = *(const float4*)(b2 + col_t * 4);
    #pragma unroll
    for (int i = 0; i < 8; ++i) {
        int row = n0 + row_t * 8 + i;
        if (row < NN) {
            float4 o;
            o.x = acc[i][0] + bv.x;
            o.y = acc[i][1] + bv.y;
            o.z = acc[i][2] + bv.z;
            o.w = acc[i][3] + bv.w;
            *(float4*)(out + (size_t)row * DD + col_t * 4) = o;
        }
    }
}

extern "C" void kernel_launch(void* const* d_in, const int* in_sizes, int n_in,
                              void* d_out, int out_size, void* d_ws, size_t ws_size,
                              hipStream_t stream) {
    const float* x  = (const float*)d_in[0];
    const int*   e0 = (const int*)d_in[1];
    const int*   e1 = (const int*)d_in[2];
    const int*   e2 = (const int*)d_in[3];
    const float* Wl = (const float*)d_in[4];
    const float* bl = (const float*)d_in[5];
    const float* Wr = (const float*)d_in[6];
    const float* P1 = (const float*)d_in[7];
    const float* b1 = (const float*)d_in[8];
    const float* P2 = (const float*)d_in[9];
    const float* b2 = (const float*)d_in[10];
    float* out = (float*)d_out;

    float* agg = (float*)d_ws;                          // R*N*D floats
    int*   cnt = (int*)(agg + (size_t)RR * NN * DD);    // R*N ints
    float* inv = (float*)(cnt + (size_t)RR * NN);       // R*N floats
    float* QB  = inv + (size_t)RR * NN;                 // 4*D*D floats
    float* cb  = QB + (size_t)4 * DD * DD;              // D floats

    hipMemsetAsync(agg, 0, (size_t)RR * NN * DD * sizeof(float), stream);
    hipMemsetAsync(cnt, 0, (size_t)RR * NN * sizeof(int), stream);

    precompute_qb_kernel<<<4 * DD, DD, 0, stream>>>(Wl, Wr, P1, QB);
    precompute_c_kernel<<<1, DD, 0, stream>>>(bl, P1, b1, cb);

    scatter_kernel<<<(3 * EE) / 4, 256, 0, stream>>>(e0, e1, e2, x, agg, cnt);
    inv_kernel<<<(RR * NN + 255) / 256, 256, 0, stream>>>(cnt, inv);

    int gblocks = (NN + 63) / 64;
    gemm1_kernel<<<gblocks, 256, 0, stream>>>(x, agg, inv, QB, cb, out);
    gemm2_kernel<<<gblocks, 256, 0, stream>>>(P2, b2, out);
}

// Round 2
// 613.556 us; speedup vs baseline: 2.5355x; 2.5355x over previous
//
#include <hip/hip_runtime.h>

#define NN 100000
#define DD 128
#define EE 500000
#define RR 3
#define MM (RR * NN)   // total buckets = 300000

// ---------------- precompute fused weights ----------------
// QB layout: [4][128][128]; seg 0 = Qx = sum_r Wr_r @ P1_r, seg 1..3 = Q_r = Wl_r @ P1_r
__global__ __launch_bounds__(128) void precompute_qb_kernel(
    const float* __restrict__ Wl, const float* __restrict__ Wr,
    const float* __restrict__ P1, float* __restrict__ QB)
{
    int s = blockIdx.x >> 7;   // 0..3
    int i = blockIdx.x & 127;  // row
    int j = threadIdx.x;       // col
    float acc = 0.f;
    if (s == 0) {
        for (int r = 0; r < RR; ++r) {
            const float* wrow = Wr + (size_t)(r * DD + i) * DD;
            const float* pcol = P1 + (size_t)(r * DD) * DD + j;
            for (int k = 0; k < DD; ++k)
                acc += wrow[k] * pcol[(size_t)k * DD];
        }
    } else {
        int r = s - 1;
        const float* wrow = Wl + (size_t)(r * DD + i) * DD;
        const float* pcol = P1 + (size_t)(r * DD) * DD + j;
        for (int k = 0; k < DD; ++k)
            acc += wrow[k] * pcol[(size_t)k * DD];
    }
    QB[(size_t)(s * DD + i) * DD + j] = acc;
}

__global__ __launch_bounds__(128) void precompute_c_kernel(
    const float* __restrict__ bl, const float* __restrict__ P1,
    const float* __restrict__ b1, float* __restrict__ cb)
{
    int j = threadIdx.x;
    float acc = b1[j];
    for (int r = 0; r < RR; ++r)
        for (int k = 0; k < DD; ++k)
            acc += bl[r * DD + k] * P1[(size_t)(r * DD + k) * DD + j];
    cb[j] = acc;
}

// ---------------- CSR build: hist -> scan -> fill ----------------
__global__ __launch_bounds__(256) void hist_kernel(
    const int* __restrict__ e0, const int* __restrict__ e1, const int* __restrict__ e2,
    int* __restrict__ cnt)
{
    int gi = blockIdx.x * 256 + threadIdx.x;
    if (gi >= RR * EE) return;
    int r = gi / EE;
    int e = gi - r * EE;
    const int* ei = (r == 0) ? e0 : (r == 1) ? e1 : e2;
    int dst = ei[EE + e];
    atomicAdd(cnt + r * NN + dst, 1);
}

// exclusive scan over MM entries: per-block prefix + block sums
__global__ __launch_bounds__(256) void scan1_kernel(
    const int* __restrict__ cnt, int* __restrict__ cursor, int* __restrict__ bsum)
{
    __shared__ int s[256];
    int t = threadIdx.x, b = blockIdx.x, i = b * 256 + t;
    int v = (i < MM) ? cnt[i] : 0;
    s[t] = v; __syncthreads();
    #pragma unroll
    for (int off = 1; off < 256; off <<= 1) {
        int tmp = (t >= off) ? s[t - off] : 0;
        __syncthreads();
        s[t] += tmp;
        __syncthreads();
    }
    if (i < MM) cursor[i] = s[t] - v;   // exclusive within block
    if (t == 255) bsum[b] = s[255];
}

__global__ __launch_bounds__(256) void scan2_kernel(int* __restrict__ bsum, int nb)
{
    __shared__ int s[256];
    int t = threadIdx.x;
    int carry = 0;
    for (int base = 0; base < nb; base += 256) {
        int v = (base + t < nb) ? bsum[base + t] : 0;
        s[t] = v; __syncthreads();
        #pragma unroll
        for (int off = 1; off < 256; off <<= 1) {
            int tmp = (t >= off) ? s[t - off] : 0;
            __syncthreads();
            s[t] += tmp;
            __syncthreads();
        }
        int total = s[255];
        if (base + t < nb) bsum[base + t] = s[t] - v + carry;
        carry += total;
        __syncthreads();
    }
}

__global__ __launch_bounds__(256) void scan3_kernel(
    int* __restrict__ cursor, const int* __restrict__ bsum)
{
    int i = blockIdx.x * 256 + threadIdx.x;
    if (i < MM) cursor[i] += bsum[blockIdx.x];
}

__global__ __launch_bounds__(256) void fill_kernel(
    const int* __restrict__ e0, const int* __restrict__ e1, const int* __restrict__ e2,
    int* __restrict__ cursor, int* __restrict__ srcidx)
{
    int gi = blockIdx.x * 256 + threadIdx.x;
    if (gi >= RR * EE) return;
    int r = gi / EE;
    int e = gi - r * EE;
    const int* ei = (r == 0) ? e0 : (r == 1) ? e1 : e2;
    int src = ei[e];
    int dst = ei[EE + e];
    int pos = atomicAdd(cursor + r * NN + dst, 1);
    srcidx[pos] = src;
}

// ---------------- gather-aggregate: one wave64 per (r,node) bucket ----------------
// after fill, cursor[bid] = end of bucket; start = end - cnt[bid]; mean folded in.
__global__ __launch_bounds__(256) void aggregate_kernel(
    const float* __restrict__ x, const int* __restrict__ srcidx,
    const int* __restrict__ cursor, const int* __restrict__ cnt,
    float* __restrict__ agg)
{
    int bid = blockIdx.x * 4 + (threadIdx.x >> 6);   // grid exact: 75000*4 = MM
    int lane = threadIdx.x & 63;
    int end = cursor[bid];
    int deg = cnt[bid];
    int start = end - deg;
    float ax = 0.f, ay = 0.f;
    for (int j = start; j < end; ++j) {
        int s = srcidx[j];
        float2 v = ((const float2*)(x + (size_t)s * DD))[lane];
        ax += v.x; ay += v.y;
    }
    float sc = 1.0f / (float)(deg > 1 ? deg : 1);
    ((float2*)(agg + (size_t)bid * DD))[lane] = make_float2(ax * sc, ay * sc);
}

// ---------------- GEMM1: h = relu([x|agg0|agg1|agg2] @ QB + cb) ----------------
__global__ __launch_bounds__(256) void gemm1_kernel(
    const float* __restrict__ x, const float* __restrict__ agg,
    const float* __restrict__ QB, const float* __restrict__ cb,
    float* __restrict__ h)
{
    __shared__ float As[64][68];      // [k][row], padded
    __shared__ float Bs[64 * 128];    // [k][j]
    int tid = threadIdx.x;
    int n0 = blockIdx.x * 64;
    int col_t = tid & 31;             // cols col_t*4 .. +3
    int row_t = tid >> 5;             // rows row_t*8 .. +7

    float acc[8][4];
    #pragma unroll
    for (int i = 0; i < 8; ++i)
        #pragma unroll
        for (int j = 0; j < 4; ++j) acc[i][j] = 0.f;

    int lrow = tid >> 2;              // 0..63  (A-load row)
    int lkq  = (tid & 3) * 16;        // k offset within chunk

    for (int chunk = 0; chunk < 8; ++chunk) {
        int seg = chunk >> 1;
        int k0 = (chunk & 1) * 64;
        const float* Aseg = (seg == 0) ? (x + (size_t)n0 * DD)
                                       : (agg + ((size_t)(seg - 1) * NN + n0) * DD);
        int grow = n0 + lrow;
        bool rok = grow < NN;

        #pragma unroll
        for (int i = 0; i < 4; ++i) {
            float4 v = make_float4(0.f, 0.f, 0.f, 0.f);
            if (rok) v = *(const float4*)(Aseg + (size_t)lrow * DD + k0 + lkq + i * 4);
            int kk = lkq + i * 4;
            As[kk + 0][lrow] = v.x;
            As[kk + 1][lrow] = v.y;
            As[kk + 2][lrow] = v.z;
            As[kk + 3][lrow] = v.w;
        }
        const float4* Bsrc = (const float4*)(QB + (size_t)(seg * DD + k0) * DD);
        float4* Bd = (float4*)Bs;
        #pragma unroll
        for (int i = 0; i < 8; ++i)
            Bd[i * 256 + tid] = Bsrc[i * 256 + tid];
        __syncthreads();

        #pragma unroll 4
        for (int kk = 0; kk < 64; ++kk) {
            float4 b = *(const float4*)(Bs + kk * 128 + col_t * 4);
            const float* ap = &As[kk][row_t * 8];
            float4 a0 = *(const float4*)(ap);
            float4 a1 = *(const float4*)(ap + 4);
            float av[8] = {a0.x, a0.y, a0.z, a0.w, a1.x, a1.y, a1.z, a1.w};
            #pragma unroll
            for (int i = 0; i < 8; ++i) {
                acc[i][0] += av[i] * b.x;
                acc[i][1] += av[i] * b.y;
                acc[i][2] += av[i] * b.z;
                acc[i][3] += av[i] * b.w;
            }
        }
        __syncthreads();
    }

    float4 cv = *(const float4*)(cb + col_t * 4);
    #pragma unroll
    for (int i = 0; i < 8; ++i) {
        int row = n0 + row_t * 8 + i;
        if (row < NN) {
            float4 o;
            o.x = acc[i][0] + cv.x;
            o.y = acc[i][1] + cv.y;
            o.z = acc[i][2] + cv.z;
            o.w = acc[i][3] + cv.w;
            o.x = o.x > 0.f ? o.x : 0.f;
            o.y = o.y > 0.f ? o.y : 0.f;
            o.z = o.z > 0.f ? o.z : 0.f;
            o.w = o.w > 0.f ? o.w : 0.f;
            *(float4*)(h + (size_t)row * DD + col_t * 4) = o;
        }
    }
}

// ---------------- GEMM2: out = h @ P2 + b2 (in-place on d_out) ----------------
__global__ __launch_bounds__(256) void gemm2_kernel(
    const float* __restrict__ P2, const float* __restrict__ b2,
    float* __restrict__ out)
{
    __shared__ float As[64][68];
    __shared__ float Bs[64 * 128];
    int tid = threadIdx.x;
    int n0 = blockIdx.x * 64;
    int col_t = tid & 31;
    int row_t = tid >> 5;

    float acc[8][4];
    #pragma unroll
    for (int i = 0; i < 8; ++i)
        #pragma unroll
        for (int j = 0; j < 4; ++j) acc[i][j] = 0.f;

    int lrow = tid >> 2;
    int lkq  = (tid & 3) * 16;

    for (int chunk = 0; chunk < 2; ++chunk) {
        int k0 = chunk * 64;
        int grow = n0 + lrow;
        bool rok = grow < NN;
        #pragma unroll
        for (int i = 0; i < 4; ++i) {
            float4 v = make_float4(0.f, 0.f, 0.f, 0.f);
            if (rok) v = *(const float4*)(out + (size_t)grow * DD + k0 + lkq + i * 4);
            int kk = lkq + i * 4;
            As[kk + 0][lrow] = v.x;
            As[kk + 1][lrow] = v.y;
            As[kk + 2][lrow] = v.z;
            As[kk + 3][lrow] = v.w;
        }
        const float4* Bsrc = (const float4*)(P2 + (size_t)k0 * DD);
        float4* Bd = (float4*)Bs;
        #pragma unroll
        for (int i = 0; i < 8; ++i)
            Bd[i * 256 + tid] = Bsrc[i * 256 + tid];
        __syncthreads();

        #pragma unroll 4
        for (int kk = 0; kk < 64; ++kk) {
            float4 b = *(const float4*)(Bs + kk * 128 + col_t * 4);
            const float* ap = &As[kk][row_t * 8];
            float4 a0 = *(const float4*)(ap);
            float4 a1 = *(const float4*)(ap + 4);
            float av[8] = {a0.x, a0.y, a0.z, a0.w, a1.x, a1.y, a1.z, a1.w};
            #pragma unroll
            for (int i = 0; i < 8; ++i) {
                acc[i][0] += av[i] * b.x;
                acc[i][1] += av[i] * b.y;
                acc[i][2] += av[i] * b.z;
                acc[i][3] += av[i] * b.w;
            }
        }
        __syncthreads();
    }

    float4 bv = *(const float4*)(b2 + col_t * 4);
    #pragma unroll
    for (int i = 0; i < 8; ++i) {
        int row = n0 + row_t * 8 + i;
        if (row < NN) {
            float4 o;
            o.x = acc[i][0] + bv.x;
            o.y = acc[i][1] + bv.y;
            o.z = acc[i][2] + bv.z;
            o.w = acc[i][3] + bv.w;
            *(float4*)(out + (size_t)row * DD + col_t * 4) = o;
        }
    }
}

extern "C" void kernel_launch(void* const* d_in, const int* in_sizes, int n_in,
                              void* d_out, int out_size, void* d_ws, size_t ws_size,
                              hipStream_t stream) {
    const float* x  = (const float*)d_in[0];
    const int*   e0 = (const int*)d_in[1];
    const int*   e1 = (const int*)d_in[2];
    const int*   e2 = (const int*)d_in[3];
    const float* Wl = (const float*)d_in[4];
    const float* bl = (const float*)d_in[5];
    const float* Wr = (const float*)d_in[6];
    const float* P1 = (const float*)d_in[7];
    const float* b1 = (const float*)d_in[8];
    const float* P2 = (const float*)d_in[9];
    const float* b2 = (const float*)d_in[10];
    float* out = (float*)d_out;

    // ws: agg [R*N*D] + QB [4*D*D] + cb [D] + bsum [2048]   (~154 MB)
    float* agg  = (float*)d_ws;
    float* QB   = agg + (size_t)RR * NN * DD;
    float* cb   = QB + (size_t)4 * DD * DD;
    int*   bsum = (int*)(cb + DD);

    // CSR scratch lives in the FRONT of d_out; its lifetime ends before
    // gemm1 overwrites d_out. Every byte is rewritten each call.
    int* srcidx = (int*)d_out;            // 3E ints  (6 MB)
    int* cnt    = srcidx + RR * EE;       // 3N ints
    int* cursor = cnt + MM;               // 3N ints  (total 8.4 MB < 51.2 MB)

    hipMemsetAsync(cnt, 0, (size_t)MM * sizeof(int), stream);

    precompute_qb_kernel<<<4 * DD, DD, 0, stream>>>(Wl, Wr, P1, QB);
    precompute_c_kernel<<<1, DD, 0, stream>>>(bl, P1, b1, cb);

    int eblocks = (RR * EE + 255) / 256;
    hist_kernel<<<eblocks, 256, 0, stream>>>(e0, e1, e2, cnt);

    int nb = (MM + 255) / 256;  // 1172
    scan1_kernel<<<nb, 256, 0, stream>>>(cnt, cursor, bsum);
    scan2_kernel<<<1, 256, 0, stream>>>(bsum, nb);
    scan3_kernel<<<nb, 256, 0, stream>>>(cursor, bsum);

    fill_kernel<<<eblocks, 256, 0, stream>>>(e0, e1, e2, cursor, srcidx);

    aggregate_kernel<<<MM / 4, 256, 0, stream>>>(x, srcidx, cursor, cnt, agg);

    int gblocks = (NN + 63) / 64;
    gemm1_kernel<<<gblocks, 256, 0, stream>>>(x, agg, QB, cb, out);
    gemm2_kernel<<<gblocks, 256, 0, stream>>>(P2, b2, out);
}

// Round 3
// 472.106 us; speedup vs baseline: 3.2952x; 1.2996x over previous
//
#include <hip/hip_runtime.h>
#include <hip/hip_bf16.h>

#define NN 100000
#define DD 128
#define EE 500000
#define RR 3
#define MM (RR * NN)   // total buckets = 300000

typedef __attribute__((ext_vector_type(8))) short   bf16x8;
typedef __attribute__((ext_vector_type(8))) ushort  ushort8;
typedef __attribute__((ext_vector_type(4))) float   f32x4;

__device__ __forceinline__ ushort f2bf(float f) {
    __hip_bfloat16 h = __float2bfloat16(f);   // RNE
    return *(ushort*)&h;
}
__device__ __forceinline__ float bflo(unsigned v) {  // low 16 bits as bf16 -> f32
    unsigned u = v << 16;
    return *(float*)&u;
}
__device__ __forceinline__ float bfhi(unsigned v) {  // high 16 bits
    unsigned u = v & 0xffff0000u;
    return *(float*)&u;
}

// ---------------- precompute fused weights (bf16, transposed) ----------------
// QBt layout: [n=128][k=512]; k = s*128+i; s0 = Qx = sum_r Wr_r@P1_r, s1..3 = Wl_r@P1_r
__global__ __launch_bounds__(128) void precompute_qbt_kernel(
    const float* __restrict__ Wl, const float* __restrict__ Wr,
    const float* __restrict__ P1, ushort* __restrict__ QBt)
{
    int s = blockIdx.x >> 7;   // 0..3
    int i = blockIdx.x & 127;  // k within segment
    int j = threadIdx.x;       // output col n
    float acc = 0.f;
    if (s == 0) {
        for (int r = 0; r < RR; ++r) {
            const float* wrow = Wr + (size_t)(r * DD + i) * DD;
            const float* pcol = P1 + (size_t)(r * DD) * DD + j;
            for (int k = 0; k < DD; ++k)
                acc += wrow[k] * pcol[(size_t)k * DD];
        }
    } else {
        int r = s - 1;
        const float* wrow = Wl + (size_t)(r * DD + i) * DD;
        const float* pcol = P1 + (size_t)(r * DD) * DD + j;
        for (int k = 0; k < DD; ++k)
            acc += wrow[k] * pcol[(size_t)k * DD];
    }
    QBt[(size_t)j * 512 + s * DD + i] = f2bf(acc);
}

__global__ __launch_bounds__(128) void precompute_p2t_kernel(
    const float* __restrict__ P2, ushort* __restrict__ P2t)
{
    int j = blockIdx.x;   // output col
    int k = threadIdx.x;
    P2t[(size_t)j * DD + k] = f2bf(P2[(size_t)k * DD + j]);
}

__global__ __launch_bounds__(128) void precompute_c_kernel(
    const float* __restrict__ bl, const float* __restrict__ P1,
    const float* __restrict__ b1, float* __restrict__ cb)
{
    int j = threadIdx.x;
    float acc = b1[j];
    for (int r = 0; r < RR; ++r)
        for (int k = 0; k < DD; ++k)
            acc += bl[r * DD + k] * P1[(size_t)(r * DD + k) * DD + j];
    cb[j] = acc;
}

// ---------------- x -> bf16 ----------------
__global__ __launch_bounds__(256) void x_tobf16_kernel(
    const float* __restrict__ x, ushort* __restrict__ xh)
{
    size_t i = (size_t)blockIdx.x * 256 + threadIdx.x;   // 4 elems each
    if (i * 4 >= (size_t)NN * DD) return;
    float4 v = ((const float4*)x)[i];
    unsigned lo = (unsigned)f2bf(v.x) | ((unsigned)f2bf(v.y) << 16);
    unsigned hi = (unsigned)f2bf(v.z) | ((unsigned)f2bf(v.w) << 16);
    ((uint2*)xh)[i] = make_uint2(lo, hi);
}

// ---------------- CSR build: hist -> scan -> fill ----------------
__global__ __launch_bounds__(256) void hist_kernel(
    const int* __restrict__ e0, const int* __restrict__ e1, const int* __restrict__ e2,
    int* __restrict__ cnt)
{
    int gi = blockIdx.x * 256 + threadIdx.x;
    if (gi >= RR * EE) return;
    int r = gi / EE;
    int e = gi - r * EE;
    const int* ei = (r == 0) ? e0 : (r == 1) ? e1 : e2;
    int dst = ei[EE + e];
    atomicAdd(cnt + r * NN + dst, 1);
}

__global__ __launch_bounds__(256) void scan1_kernel(
    const int* __restrict__ cnt, int* __restrict__ cursor, int* __restrict__ bsum)
{
    __shared__ int s[256];
    int t = threadIdx.x, b = blockIdx.x, i = b * 256 + t;
    int v = (i < MM) ? cnt[i] : 0;
    s[t] = v; __syncthreads();
    #pragma unroll
    for (int off = 1; off < 256; off <<= 1) {
        int tmp = (t >= off) ? s[t - off] : 0;
        __syncthreads();
        s[t] += tmp;
        __syncthreads();
    }
    if (i < MM) cursor[i] = s[t] - v;
    if (t == 255) bsum[b] = s[255];
}

__global__ __launch_bounds__(256) void scan2_kernel(int* __restrict__ bsum, int nb)
{
    __shared__ int s[256];
    int t = threadIdx.x;
    int carry = 0;
    for (int base = 0; base < nb; base += 256) {
        int v = (base + t < nb) ? bsum[base + t] : 0;
        s[t] = v; __syncthreads();
        #pragma unroll
        for (int off = 1; off < 256; off <<= 1) {
            int tmp = (t >= off) ? s[t - off] : 0;
            __syncthreads();
            s[t] += tmp;
            __syncthreads();
        }
        int total = s[255];
        if (base + t < nb) bsum[base + t] = s[t] - v + carry;
        carry += total;
        __syncthreads();
    }
}

__global__ __launch_bounds__(256) void scan3_kernel(
    int* __restrict__ cursor, const int* __restrict__ bsum)
{
    int i = blockIdx.x * 256 + threadIdx.x;
    if (i < MM) cursor[i] += bsum[blockIdx.x];
}

__global__ __launch_bounds__(256) void fill_kernel(
    const int* __restrict__ e0, const int* __restrict__ e1, const int* __restrict__ e2,
    int* __restrict__ cursor, int* __restrict__ srcidx)
{
    int gi = blockIdx.x * 256 + threadIdx.x;
    if (gi >= RR * EE) return;
    int r = gi / EE;
    int e = gi - r * EE;
    const int* ei = (r == 0) ? e0 : (r == 1) ? e1 : e2;
    int src = ei[e];
    int dst = ei[EE + e];
    int pos = atomicAdd(cursor + r * NN + dst, 1);
    srcidx[pos] = src;
}

// ---------------- gather-aggregate (bf16 rows, f32 accum, bf16 out) ----------------
__global__ __launch_bounds__(256) void aggregate_kernel(
    const ushort* __restrict__ xh, const int* __restrict__ srcidx,
    const int* __restrict__ cursor, const int* __restrict__ cnt,
    ushort* __restrict__ aggh)
{
    int bid = blockIdx.x * 4 + (threadIdx.x >> 6);   // grid exact: 75000*4 = MM
    int lane = threadIdx.x & 63;
    int end = cursor[bid];
    int deg = cnt[bid];
    int start = end - deg;
    float ax = 0.f, ay = 0.f;
    for (int j = start; j < end; ++j) {
        int s = srcidx[j];
        unsigned v = ((const unsigned*)(xh + (size_t)s * DD))[lane];
        ax += bflo(v);
        ay += bfhi(v);
    }
    float sc = 1.0f / (float)(deg > 1 ? deg : 1);
    unsigned o = (unsigned)f2bf(ax * sc) | ((unsigned)f2bf(ay * sc) << 16);
    ((unsigned*)(aggh + (size_t)bid * DD))[lane] = o;
}

// ---------------- GEMM1 (MFMA): hh = relu([xh|agg0|agg1|agg2] @ QBt^T + cb) ---------
// 128x128 tile, 4 waves (2x2), per-wave 64x64, BK=64 staged in LDS.
__global__ __launch_bounds__(256) void gemm1_kernel(
    const ushort* __restrict__ xh, const ushort* __restrict__ aggh,
    const ushort* __restrict__ QBt, const float* __restrict__ cb,
    ushort* __restrict__ hh)
{
    __shared__ ushort As[128][72];   // [m][k], pad 8
    __shared__ ushort Bs[128][72];   // [n][k], pad 8
    int tid = threadIdx.x;
    int n0 = blockIdx.x * 128;
    int wid = tid >> 6;
    int lane = tid & 63;
    int wr = wid >> 1, wc = wid & 1;
    int lrow = lane & 15;
    int lk = (lane >> 4) * 8;

    f32x4 acc[4][4];
    #pragma unroll
    for (int i = 0; i < 4; ++i)
        #pragma unroll
        for (int j = 0; j < 4; ++j) acc[i][j] = (f32x4){0.f, 0.f, 0.f, 0.f};

    for (int c = 0; c < 8; ++c) {
        int seg = c >> 1;
        int kloc = (c & 1) * 64;
        const ushort* Abase = (seg == 0) ? xh : (aggh + (size_t)(seg - 1) * NN * DD);
        if (c) __syncthreads();
        #pragma unroll
        for (int i = 0; i < 4; ++i) {
            int id = tid + i * 256;
            int row = id >> 3;
            int s16 = id & 7;
            int grow = n0 + row;
            ushort8 v = {0, 0, 0, 0, 0, 0, 0, 0};
            if (grow < NN)
                v = *(const ushort8*)(Abase + (size_t)grow * DD + kloc + s16 * 8);
            *(ushort8*)&As[row][s16 * 8] = v;
        }
        #pragma unroll
        for (int i = 0; i < 4; ++i) {
            int id = tid + i * 256;
            int n = id >> 3;
            int s16 = id & 7;
            *(ushort8*)&Bs[n][s16 * 8] =
                *(const ushort8*)(QBt + (size_t)n * 512 + c * 64 + s16 * 8);
        }
        __syncthreads();
        #pragma unroll
        for (int ks = 0; ks < 2; ++ks) {
            bf16x8 a[4], b[4];
            #pragma unroll
            for (int mi = 0; mi < 4; ++mi)
                a[mi] = *(const bf16x8*)&As[wr * 64 + mi * 16 + lrow][ks * 32 + lk];
            #pragma unroll
            for (int ni = 0; ni < 4; ++ni)
                b[ni] = *(const bf16x8*)&Bs[wc * 64 + ni * 16 + lrow][ks * 32 + lk];
            #pragma unroll
            for (int mi = 0; mi < 4; ++mi)
                #pragma unroll
                for (int ni = 0; ni < 4; ++ni)
                    acc[mi][ni] = __builtin_amdgcn_mfma_f32_16x16x32_bf16(
                        a[mi], b[ni], acc[mi][ni], 0, 0, 0);
        }
    }

    int crow = lane >> 4;    // C/D: row=(lane>>4)*4+q, col=lane&15  [m89/m91]
    int ccol = lane & 15;
    #pragma unroll
    for (int ni = 0; ni < 4; ++ni) {
        int gcol = wc * 64 + ni * 16 + ccol;
        float cv = cb[gcol];
        #pragma unroll
        for (int mi = 0; mi < 4; ++mi) {
            #pragma unroll
            for (int q = 0; q < 4; ++q) {
                int gr = n0 + wr * 64 + mi * 16 + crow * 4 + q;
                if (gr < NN) {
                    float v = acc[mi][ni][q] + cv;
                    v = v > 0.f ? v : 0.f;
                    hh[(size_t)gr * DD + gcol] = f2bf(v);
                }
            }
        }
    }
}

// ---------------- GEMM2 (MFMA): out = hh @ P2t^T + b2 ----------------
__global__ __launch_bounds__(256) void gemm2_kernel(
    const ushort* __restrict__ hh, const ushort* __restrict__ P2t,
    const float* __restrict__ b2, float* __restrict__ out)
{
    __shared__ ushort As[128][72];
    __shared__ ushort Bs[128][72];
    int tid = threadIdx.x;
    int n0 = blockIdx.x * 128;
    int wid = tid >> 6;
    int lane = tid & 63;
    int wr = wid >> 1, wc = wid & 1;
    int lrow = lane & 15;
    int lk = (lane >> 4) * 8;

    f32x4 acc[4][4];
    #pragma unroll
    for (int i = 0; i < 4; ++i)
        #pragma unroll
        for (int j = 0; j < 4; ++j) acc[i][j] = (f32x4){0.f, 0.f, 0.f, 0.f};

    for (int c = 0; c < 2; ++c) {
        int kloc = c * 64;
        if (c) __syncthreads();
        #pragma unroll
        for (int i = 0; i < 4; ++i) {
            int id = tid + i * 256;
            int row = id >> 3;
            int s16 = id & 7;
            int grow = n0 + row;
            ushort8 v = {0, 0, 0, 0, 0, 0, 0, 0};
            if (grow < NN)
                v = *(const ushort8*)(hh + (size_t)grow * DD + kloc + s16 * 8);
            *(ushort8*)&As[row][s16 * 8] = v;
        }
        #pragma unroll
        for (int i = 0; i < 4; ++i) {
            int id = tid + i * 256;
            int n = id >> 3;
            int s16 = id & 7;
            *(ushort8*)&Bs[n][s16 * 8] =
                *(const ushort8*)(P2t + (size_t)n * DD + kloc + s16 * 8);
        }
        __syncthreads();
        #pragma unroll
        for (int ks = 0; ks < 2; ++ks) {
            bf16x8 a[4], b[4];
            #pragma unroll
            for (int mi = 0; mi < 4; ++mi)
                a[mi] = *(const bf16x8*)&As[wr * 64 + mi * 16 + lrow][ks * 32 + lk];
            #pragma unroll
            for (int ni = 0; ni < 4; ++ni)
                b[ni] = *(const bf16x8*)&Bs[wc * 64 + ni * 16 + lrow][ks * 32 + lk];
            #pragma unroll
            for (int mi = 0; mi < 4; ++mi)
                #pragma unroll
                for (int ni = 0; ni < 4; ++ni)
                    acc[mi][ni] = __builtin_amdgcn_mfma_f32_16x16x32_bf16(
                        a[mi], b[ni], acc[mi][ni], 0, 0, 0);
        }
    }

    int crow = lane >> 4;
    int ccol = lane & 15;
    #pragma unroll
    for (int ni = 0; ni < 4; ++ni) {
        int gcol = wc * 64 + ni * 16 + ccol;
        float bv = b2[gcol];
        #pragma unroll
        for (int mi = 0; mi < 4; ++mi) {
            #pragma unroll
            for (int q = 0; q < 4; ++q) {
                int gr = n0 + wr * 64 + mi * 16 + crow * 4 + q;
                if (gr < NN)
                    out[(size_t)gr * DD + gcol] = acc[mi][ni][q] + bv;
            }
        }
    }
}

extern "C" void kernel_launch(void* const* d_in, const int* in_sizes, int n_in,
                              void* d_out, int out_size, void* d_ws, size_t ws_size,
                              hipStream_t stream) {
    const float* x  = (const float*)d_in[0];
    const int*   e0 = (const int*)d_in[1];
    const int*   e1 = (const int*)d_in[2];
    const int*   e2 = (const int*)d_in[3];
    const float* Wl = (const float*)d_in[4];
    const float* bl = (const float*)d_in[5];
    const float* Wr = (const float*)d_in[6];
    const float* P1 = (const float*)d_in[7];
    const float* b1 = (const float*)d_in[8];
    const float* P2 = (const float*)d_in[9];
    const float* b2 = (const float*)d_in[10];
    float* out = (float*)d_out;

    // ws layout (~128 MB)
    ushort* xh   = (ushort*)d_ws;                         // N*D
    ushort* aggh = xh + (size_t)NN * DD;                  // R*N*D
    ushort* hh   = aggh + (size_t)RR * NN * DD;           // N*D
    ushort* QBt  = hh + (size_t)NN * DD;                  // 128*512
    ushort* P2t  = QBt + (size_t)128 * 512;               // 128*128
    float*  cb   = (float*)(P2t + (size_t)DD * DD);       // D
    int*    bsum = (int*)(cb + DD);                       // ~2048

    // CSR scratch in the FRONT of d_out; lifetime ends before gemm2 writes out.
    int* srcidx = (int*)d_out;            // 3E ints
    int* cnt    = srcidx + RR * EE;       // 3N ints
    int* cursor = cnt + MM;               // 3N ints (8.4 MB total < 51.2 MB)

    hipMemsetAsync(cnt, 0, (size_t)MM * sizeof(int), stream);

    precompute_qbt_kernel<<<4 * DD, DD, 0, stream>>>(Wl, Wr, P1, QBt);
    precompute_p2t_kernel<<<DD, DD, 0, stream>>>(P2, P2t);
    precompute_c_kernel<<<1, DD, 0, stream>>>(bl, P1, b1, cb);

    x_tobf16_kernel<<<(NN * DD / 4 + 255) / 256, 256, 0, stream>>>(x, xh);

    int eblocks = (RR * EE + 255) / 256;
    hist_kernel<<<eblocks, 256, 0, stream>>>(e0, e1, e2, cnt);

    int nb = (MM + 255) / 256;
    scan1_kernel<<<nb, 256, 0, stream>>>(cnt, cursor, bsum);
    scan2_kernel<<<1, 256, 0, stream>>>(bsum, nb);
    scan3_kernel<<<nb, 256, 0, stream>>>(cursor, bsum);

    fill_kernel<<<eblocks, 256, 0, stream>>>(e0, e1, e2, cursor, srcidx);

    aggregate_kernel<<<MM / 4, 256, 0, stream>>>(xh, srcidx, cursor, cnt, aggh);

    int gblocks = (NN + 127) / 128;
    gemm1_kernel<<<gblocks, 256, 0, stream>>>(xh, aggh, QBt, cb, hh);
    gemm2_kernel<<<gblocks, 256, 0, stream>>>(hh, P2t, b2, out);
}

// Round 5
// 367.803 us; speedup vs baseline: 4.2297x; 1.2836x over previous
//
#include <hip/hip_runtime.h>
#include <hip/hip_bf16.h>

#define NN 100000
#define DD 128
#define EE 500000
#define RR 3
#define MM (RR * NN)   // total buckets = 300000

typedef __attribute__((ext_vector_type(8))) short   bf16x8;
typedef __attribute__((ext_vector_type(8))) ushort  ushort8;
typedef __attribute__((ext_vector_type(4))) float   f32x4;

__device__ __forceinline__ ushort f2bf(float f) {
    __hip_bfloat16 h = __float2bfloat16(f);   // RNE
    return *(ushort*)&h;
}
__device__ __forceinline__ float bflo(unsigned v) {
    unsigned u = v << 16;
    return *(float*)&u;
}
__device__ __forceinline__ float bfhi(unsigned v) {
    unsigned u = v & 0xffff0000u;
    return *(float*)&u;
}

// ---------------- precompute fused weights (bf16, transposed) ----------------
// QBt layout: [n=128][k=512]; k = s*128+i; s0 = Qx = sum_r Wr_r@P1_r, s1..3 = Wl_r@P1_r
__global__ __launch_bounds__(128) void precompute_qbt_kernel(
    const float* __restrict__ Wl, const float* __restrict__ Wr,
    const float* __restrict__ P1, ushort* __restrict__ QBt)
{
    int s = blockIdx.x >> 7;   // 0..3
    int i = blockIdx.x & 127;  // k within segment
    int j = threadIdx.x;       // output col n
    float acc = 0.f;
    if (s == 0) {
        for (int r = 0; r < RR; ++r) {
            const float* wrow = Wr + (size_t)(r * DD + i) * DD;
            const float* pcol = P1 + (size_t)(r * DD) * DD + j;
            for (int k = 0; k < DD; ++k)
                acc += wrow[k] * pcol[(size_t)k * DD];
        }
    } else {
        int r = s - 1;
        const float* wrow = Wl + (size_t)(r * DD + i) * DD;
        const float* pcol = P1 + (size_t)(r * DD) * DD + j;
        for (int k = 0; k < DD; ++k)
            acc += wrow[k] * pcol[(size_t)k * DD];
    }
    QBt[(size_t)j * 512 + s * DD + i] = f2bf(acc);
}

__global__ __launch_bounds__(128) void precompute_p2t_kernel(
    const float* __restrict__ P2, ushort* __restrict__ P2t)
{
    int j = blockIdx.x;   // output col
    int k = threadIdx.x;
    P2t[(size_t)j * DD + k] = f2bf(P2[(size_t)k * DD + j]);
}

__global__ __launch_bounds__(128) void precompute_c_kernel(
    const float* __restrict__ bl, const float* __restrict__ P1,
    const float* __restrict__ b1, float* __restrict__ cb)
{
    int j = threadIdx.x;
    float acc = b1[j];
    for (int r = 0; r < RR; ++r)
        for (int k = 0; k < DD; ++k)
            acc += bl[r * DD + k] * P1[(size_t)(r * DD + k) * DD + j];
    cb[j] = acc;
}

// ---------------- x -> bf16 ----------------
__global__ __launch_bounds__(256) void x_tobf16_kernel(
    const float* __restrict__ x, ushort* __restrict__ xh)
{
    size_t i = (size_t)blockIdx.x * 256 + threadIdx.x;   // 4 elems each
    if (i * 4 >= (size_t)NN * DD) return;
    float4 v = ((const float4*)x)[i];
    unsigned lo = (unsigned)f2bf(v.x) | ((unsigned)f2bf(v.y) << 16);
    unsigned hi = (unsigned)f2bf(v.z) | ((unsigned)f2bf(v.w) << 16);
    ((uint2*)xh)[i] = make_uint2(lo, hi);
}

// ---------------- CSR build: hist -> scan -> fill ----------------
__global__ __launch_bounds__(256) void hist_kernel(
    const int* __restrict__ e0, const int* __restrict__ e1, const int* __restrict__ e2,
    int* __restrict__ cnt)
{
    int gi = blockIdx.x * 256 + threadIdx.x;
    if (gi >= RR * EE) return;
    int r = gi / EE;
    int e = gi - r * EE;
    const int* ei = (r == 0) ? e0 : (r == 1) ? e1 : e2;
    int dst = ei[EE + e];
    atomicAdd(cnt + r * NN + dst, 1);
}

__global__ __launch_bounds__(256) void scan1_kernel(
    const int* __restrict__ cnt, int* __restrict__ cursor, int* __restrict__ bsum)
{
    __shared__ int s[256];
    int t = threadIdx.x, b = blockIdx.x, i = b * 256 + t;
    int v = (i < MM) ? cnt[i] : 0;
    s[t] = v; __syncthreads();
    #pragma unroll
    for (int off = 1; off < 256; off <<= 1) {
        int tmp = (t >= off) ? s[t - off] : 0;
        __syncthreads();
        s[t] += tmp;
        __syncthreads();
    }
    if (i < MM) cursor[i] = s[t] - v;   // exclusive within block
    if (t == 255) bsum[b] = s[255];
}

__global__ __launch_bounds__(256) void scan2_kernel(int* __restrict__ bsum, int nb)
{
    __shared__ int s[256];
    int t = threadIdx.x;
    int carry = 0;
    for (int base = 0; base < nb; base += 256) {
        int v = (base + t < nb) ? bsum[base + t] : 0;
        s[t] = v; __syncthreads();
        #pragma unroll
        for (int off = 1; off < 256; off <<= 1) {
            int tmp = (t >= off) ? s[t - off] : 0;
            __syncthreads();
            s[t] += tmp;
            __syncthreads();
        }
        int total = s[255];
        if (base + t < nb) bsum[base + t] = s[t] - v + carry;
        carry += total;
        __syncthreads();
    }
}

// fill: global pos = (local atomic on cursor) + bsum[bucket block]
__global__ __launch_bounds__(256) void fill_kernel(
    const int* __restrict__ e0, const int* __restrict__ e1, const int* __restrict__ e2,
    int* __restrict__ cursor, const int* __restrict__ bsum, int* __restrict__ srcidx)
{
    int gi = blockIdx.x * 256 + threadIdx.x;
    if (gi >= RR * EE) return;
    int r = gi / EE;
    int e = gi - r * EE;
    const int* ei = (r == 0) ? e0 : (r == 1) ? e1 : e2;
    int src = ei[e];
    int dst = ei[EE + e];
    int b = r * NN + dst;
    int pos = atomicAdd(cursor + b, 1) + bsum[b >> 8];
    srcidx[pos] = src;
}

// ---------------- gather-aggregate: predicated unroll-4 for MLP ----------------
__global__ __launch_bounds__(256) void aggregate_kernel(
    const ushort* __restrict__ xh, const int* __restrict__ srcidx,
    const int* __restrict__ cursor, const int* __restrict__ cnt,
    const int* __restrict__ bsum, ushort* __restrict__ aggh)
{
    int bid = blockIdx.x * 4 + (threadIdx.x >> 6);   // grid exact: 75000*4 = MM
    int lane = threadIdx.x & 63;
    int deg = cnt[bid];
    int end = cursor[bid] + bsum[bid >> 8];          // cursor = local_excl + deg
    int start = end - deg;
    const unsigned* xu = (const unsigned*)xh;
    float ax = 0.f, ay = 0.f;
    for (int j = start; j < end; j += 4) {
        int e1 = end - 1;
        int j1 = (j + 1 < e1) ? j + 1 : e1;
        int j2 = (j + 2 < e1) ? j + 2 : e1;
        int j3 = (j + 3 < e1) ? j + 3 : e1;
        int s0 = srcidx[j], s1 = srcidx[j1], s2 = srcidx[j2], s3 = srcidx[j3];
        unsigned v0 = xu[(size_t)s0 * 64 + lane];
        unsigned v1 = xu[(size_t)s1 * 64 + lane];
        unsigned v2 = xu[(size_t)s2 * 64 + lane];
        unsigned v3 = xu[(size_t)s3 * 64 + lane];
        v1 = (j + 1 < end) ? v1 : 0u;
        v2 = (j + 2 < end) ? v2 : 0u;
        v3 = (j + 3 < end) ? v3 : 0u;
        ax += bflo(v0) + bflo(v1) + bflo(v2) + bflo(v3);
        ay += bfhi(v0) + bfhi(v1) + bfhi(v2) + bfhi(v3);
    }
    float sc = 1.0f / (float)(deg > 1 ? deg : 1);
    unsigned o = (unsigned)f2bf(ax * sc) | ((unsigned)f2bf(ay * sc) << 16);
    ((unsigned*)(aggh + (size_t)bid * DD))[lane] = o;
}

// ---------------- fused GEMM: out = relu([xh|agg]@QBt^T + cb) @ P2t^T + b2 ----------
// Stage1: 128x128 h-tile via 8 K-chunks (As/Bs in LDS). h -> LDS (bf16).
// Stage2: K=128 fully local: h_tile @ P2 -> out.
// LDS union: stage1 As[128][72]+Bs[128][72] = 36,864 B; stage2 Hs[128][136]+Ps[128][136]
// = 69,632 B  ->  S = 34,816 ushorts (69.6 KB, 2 blocks/CU).
__global__ __launch_bounds__(256) void gemm_fused_kernel(
    const ushort* __restrict__ xh, const ushort* __restrict__ aggh,
    const ushort* __restrict__ QBt, const float* __restrict__ cb,
    const ushort* __restrict__ P2t, const float* __restrict__ b2,
    float* __restrict__ out)
{
    __shared__ ushort S[34816];                        // 69,632 B
    ushort (*As)[72]  = (ushort(*)[72])S;              // stage1 A  [128][72]
    ushort (*Bs)[72]  = (ushort(*)[72])(S + 9216);     // stage1 B  [128][72]
    ushort (*Hs)[136] = (ushort(*)[136])S;             // stage2 A  [128][136]
    ushort (*Ps)[136] = (ushort(*)[136])(S + 17408);   // stage2 B  [128][136]

    int tid = threadIdx.x;
    int n0 = blockIdx.x * 128;
    int wid = tid >> 6;
    int lane = tid & 63;
    int wr = wid >> 1, wc = wid & 1;
    int lrow = lane & 15;
    int lk = (lane >> 4) * 8;

    f32x4 acc[4][4];
    #pragma unroll
    for (int i = 0; i < 4; ++i)
        #pragma unroll
        for (int j = 0; j < 4; ++j) acc[i][j] = (f32x4){0.f, 0.f, 0.f, 0.f};

    for (int c = 0; c < 8; ++c) {
        int seg = c >> 1;
        int kloc = (c & 1) * 64;
        const ushort* Abase = (seg == 0) ? xh : (aggh + (size_t)(seg - 1) * NN * DD);
        if (c) __syncthreads();
        #pragma unroll
        for (int i = 0; i < 4; ++i) {
            int id = tid + i * 256;
            int row = id >> 3;
            int s16 = id & 7;
            int grow = n0 + row;
            ushort8 v = {0, 0, 0, 0, 0, 0, 0, 0};
            if (grow < NN)
                v = *(const ushort8*)(Abase + (size_t)grow * DD + kloc + s16 * 8);
            *(ushort8*)&As[row][s16 * 8] = v;
        }
        #pragma unroll
        for (int i = 0; i < 4; ++i) {
            int id = tid + i * 256;
            int n = id >> 3;
            int s16 = id & 7;
            *(ushort8*)&Bs[n][s16 * 8] =
                *(const ushort8*)(QBt + (size_t)n * 512 + c * 64 + s16 * 8);
        }
        __syncthreads();
        #pragma unroll
        for (int ks = 0; ks < 2; ++ks) {
            bf16x8 a[4], b[4];
            #pragma unroll
            for (int mi = 0; mi < 4; ++mi)
                a[mi] = *(const bf16x8*)&As[wr * 64 + mi * 16 + lrow][ks * 32 + lk];
            #pragma unroll
            for (int ni = 0; ni < 4; ++ni)
                b[ni] = *(const bf16x8*)&Bs[wc * 64 + ni * 16 + lrow][ks * 32 + lk];
            #pragma unroll
            for (int mi = 0; mi < 4; ++mi)
                #pragma unroll
                for (int ni = 0; ni < 4; ++ni)
                    acc[mi][ni] = __builtin_amdgcn_mfma_f32_16x16x32_bf16(
                        a[mi], b[ni], acc[mi][ni], 0, 0, 0);
        }
    }

    __syncthreads();   // all stage1 LDS reads done before repurposing

    // epilogue1: h = relu(acc + cb) -> Hs (bf16); C/D layout row=(lane>>4)*4+q, col=lane&15
    int crow = lane >> 4;
    int ccol = lane & 15;
    #pragma unroll
    for (int ni = 0; ni < 4; ++ni) {
        int gcol = wc * 64 + ni * 16 + ccol;
        float cv = cb[gcol];
        #pragma unroll
        for (int mi = 0; mi < 4; ++mi) {
            #pragma unroll
            for (int q = 0; q < 4; ++q) {
                float v = acc[mi][ni][q] + cv;
                v = v > 0.f ? v : 0.f;
                Hs[wr * 64 + mi * 16 + crow * 4 + q][gcol] = f2bf(v);
            }
        }
    }
    // stage P2t: 128 rows x 128 k (16 ushort8 per row)
    #pragma unroll
    for (int i = 0; i < 8; ++i) {
        int id = tid + i * 256;
        int n = id >> 4, cc = id & 15;
        *(ushort8*)&Ps[n][cc * 8] = *(const ushort8*)(P2t + (size_t)n * DD + cc * 8);
    }
    __syncthreads();

    f32x4 acc2[4][4];
    #pragma unroll
    for (int i = 0; i < 4; ++i)
        #pragma unroll
        for (int j = 0; j < 4; ++j) acc2[i][j] = (f32x4){0.f, 0.f, 0.f, 0.f};

    #pragma unroll
    for (int ks = 0; ks < 4; ++ks) {
        bf16x8 a[4], b[4];
        #pragma unroll
        for (int mi = 0; mi < 4; ++mi)
            a[mi] = *(const bf16x8*)&Hs[wr * 64 + mi * 16 + lrow][ks * 32 + lk];
        #pragma unroll
        for (int ni = 0; ni < 4; ++ni)
            b[ni] = *(const bf16x8*)&Ps[wc * 64 + ni * 16 + lrow][ks * 32 + lk];
        #pragma unroll
        for (int mi = 0; mi < 4; ++mi)
            #pragma unroll
            for (int ni = 0; ni < 4; ++ni)
                acc2[mi][ni] = __builtin_amdgcn_mfma_f32_16x16x32_bf16(
                    a[mi], b[ni], acc2[mi][ni], 0, 0, 0);
    }

    #pragma unroll
    for (int ni = 0; ni < 4; ++ni) {
        int gcol = wc * 64 + ni * 16 + ccol;
        float bv = b2[gcol];
        #pragma unroll
        for (int mi = 0; mi < 4; ++mi) {
            #pragma unroll
            for (int q = 0; q < 4; ++q) {
                int gr = n0 + wr * 64 + mi * 16 + crow * 4 + q;
                if (gr < NN)
                    out[(size_t)gr * DD + gcol] = acc2[mi][ni][q] + bv;
            }
        }
    }
}

extern "C" void kernel_launch(void* const* d_in, const int* in_sizes, int n_in,
                              void* d_out, int out_size, void* d_ws, size_t ws_size,
                              hipStream_t stream) {
    const float* x  = (const float*)d_in[0];
    const int*   e0 = (const int*)d_in[1];
    const int*   e1 = (const int*)d_in[2];
    const int*   e2 = (const int*)d_in[3];
    const float* Wl = (const float*)d_in[4];
    const float* bl = (const float*)d_in[5];
    const float* Wr = (const float*)d_in[6];
    const float* P1 = (const float*)d_in[7];
    const float* b1 = (const float*)d_in[8];
    const float* P2 = (const float*)d_in[9];
    const float* b2 = (const float*)d_in[10];
    float* out = (float*)d_out;

    // ws layout
    ushort* xh   = (ushort*)d_ws;                         // N*D
    ushort* aggh = xh + (size_t)NN * DD;                  // R*N*D
    ushort* QBt  = aggh + (size_t)RR * NN * DD;           // 128*512
    ushort* P2t  = QBt + (size_t)128 * 512;               // 128*128
    float*  cb   = (float*)(P2t + (size_t)DD * DD);       // D
    int*    bsum = (int*)(cb + DD);                       // ~2048

    // CSR scratch in the FRONT of d_out; lifetime ends before gemm_fused writes out.
    int* srcidx = (int*)d_out;            // 3E ints
    int* cnt    = srcidx + RR * EE;       // 3N ints
    int* cursor = cnt + MM;               // 3N ints (8.4 MB total < 51.2 MB)

    hipMemsetAsync(cnt, 0, (size_t)MM * sizeof(int), stream);

    precompute_qbt_kernel<<<4 * DD, DD, 0, stream>>>(Wl, Wr, P1, QBt);
    precompute_p2t_kernel<<<DD, DD, 0, stream>>>(P2, P2t);
    precompute_c_kernel<<<1, DD, 0, stream>>>(bl, P1, b1, cb);

    x_tobf16_kernel<<<(NN * DD / 4 + 255) / 256, 256, 0, stream>>>(x, xh);

    int eblocks = (RR * EE + 255) / 256;
    hist_kernel<<<eblocks, 256, 0, stream>>>(e0, e1, e2, cnt);

    int nb = (MM + 255) / 256;
    scan1_kernel<<<nb, 256, 0, stream>>>(cnt, cursor, bsum);
    scan2_kernel<<<1, 256, 0, stream>>>(bsum, nb);

    fill_kernel<<<eblocks, 256, 0, stream>>>(e0, e1, e2, cursor, bsum, srcidx);

    aggregate_kernel<<<MM / 4, 256, 0, stream>>>(xh, srcidx, cursor, cnt, bsum, aggh);

    int gblocks = (NN + 127) / 128;
    gemm_fused_kernel<<<gblocks, 256, 0, stream>>>(xh, aggh, QBt, cb, P2t, b2, out);
}

// Round 6
// 292.265 us; speedup vs baseline: 5.3229x; 1.2585x over previous
//
#include <hip/hip_runtime.h>
#include <hip/hip_bf16.h>

#define NN 100000
#define DD 128
#define EE 500000
#define RR 3
#define MM (RR * NN)   // total buckets = 300000
#define CAP 32         // max neighbors stored per bucket (Poisson(5): P(deg>32)~1e-15)

typedef __attribute__((ext_vector_type(8))) short   bf16x8;
typedef __attribute__((ext_vector_type(8))) ushort  ushort8;
typedef __attribute__((ext_vector_type(4))) float   f32x4;

__device__ __forceinline__ ushort f2bf(float f) {
    __hip_bfloat16 h = __float2bfloat16(f);   // RNE
    return *(ushort*)&h;
}
__device__ __forceinline__ float bflo(unsigned v) {
    unsigned u = v << 16;
    return *(float*)&u;
}
__device__ __forceinline__ float bfhi(unsigned v) {
    unsigned u = v & 0xffff0000u;
    return *(float*)&u;
}

// ---------------- precompute fused weights (bf16, transposed) ----------------
// QBt layout: [n=128][k=512]; k = s*128+i; s0 = Qx = sum_r Wr_r@P1_r, s1..3 = Wl_r@P1_r
__global__ __launch_bounds__(128) void precompute_qbt_kernel(
    const float* __restrict__ Wl, const float* __restrict__ Wr,
    const float* __restrict__ P1, ushort* __restrict__ QBt)
{
    int s = blockIdx.x >> 7;   // 0..3
    int i = blockIdx.x & 127;  // k within segment
    int j = threadIdx.x;       // output col n
    float acc = 0.f;
    if (s == 0) {
        for (int r = 0; r < RR; ++r) {
            const float* wrow = Wr + (size_t)(r * DD + i) * DD;
            const float* pcol = P1 + (size_t)(r * DD) * DD + j;
            for (int k = 0; k < DD; ++k)
                acc += wrow[k] * pcol[(size_t)k * DD];
        }
    } else {
        int r = s - 1;
        const float* wrow = Wl + (size_t)(r * DD + i) * DD;
        const float* pcol = P1 + (size_t)(r * DD) * DD + j;
        for (int k = 0; k < DD; ++k)
            acc += wrow[k] * pcol[(size_t)k * DD];
    }
    QBt[(size_t)j * 512 + s * DD + i] = f2bf(acc);
}

__global__ __launch_bounds__(128) void precompute_p2t_kernel(
    const float* __restrict__ P2, ushort* __restrict__ P2t)
{
    int j = blockIdx.x;   // output col
    int k = threadIdx.x;
    P2t[(size_t)j * DD + k] = f2bf(P2[(size_t)k * DD + j]);
}

__global__ __launch_bounds__(128) void precompute_c_kernel(
    const float* __restrict__ bl, const float* __restrict__ P1,
    const float* __restrict__ b1, float* __restrict__ cb)
{
    int j = threadIdx.x;
    float acc = b1[j];
    for (int r = 0; r < RR; ++r)
        for (int k = 0; k < DD; ++k)
            acc += bl[r * DD + k] * P1[(size_t)(r * DD + k) * DD + j];
    cb[j] = acc;
}

// ---------------- x -> bf16 ----------------
__global__ __launch_bounds__(256) void x_tobf16_kernel(
    const float* __restrict__ x, ushort* __restrict__ xh)
{
    size_t i = (size_t)blockIdx.x * 256 + threadIdx.x;   // 4 elems each
    if (i * 4 >= (size_t)NN * DD) return;
    float4 v = ((const float4*)x)[i];
    unsigned lo = (unsigned)f2bf(v.x) | ((unsigned)f2bf(v.y) << 16);
    unsigned hi = (unsigned)f2bf(v.z) | ((unsigned)f2bf(v.w) << 16);
    ((uint2*)xh)[i] = make_uint2(lo, hi);
}

// ---------------- merged hist+fill: one pass, padded buckets ----------------
__global__ __launch_bounds__(256) void fill_kernel(
    const int* __restrict__ e0, const int* __restrict__ e1, const int* __restrict__ e2,
    int* __restrict__ cnt, int* __restrict__ srcidx)
{
    int gi = blockIdx.x * 256 + threadIdx.x;
    if (gi >= RR * EE) return;
    int r = gi / EE;
    int e = gi - r * EE;
    const int* ei = (r == 0) ? e0 : (r == 1) ? e1 : e2;
    int src = ei[e];
    int dst = ei[EE + e];
    int b = r * NN + dst;
    int slot = atomicAdd(cnt + b, 1);
    if (slot < CAP) srcidx[(size_t)b * CAP + slot] = src;
}

// ---------------- gather-aggregate: predicated unroll-8 for MLP ----------------
__global__ __launch_bounds__(256) void aggregate_kernel(
    const ushort* __restrict__ xh, const int* __restrict__ srcidx,
    const int* __restrict__ cnt, ushort* __restrict__ aggh)
{
    int bid = blockIdx.x * 4 + (threadIdx.x >> 6);   // grid exact: 75000*4 = MM
    int lane = threadIdx.x & 63;
    int deg = cnt[bid];
    int degc = deg < CAP ? deg : CAP;                // stored count
    const int* sbase = srcidx + (size_t)bid * CAP;
    const unsigned* xu = (const unsigned*)xh;
    float ax = 0.f, ay = 0.f;
    int last = degc - 1;
    for (int j = 0; j < degc; j += 8) {
        int s[8];
        #pragma unroll
        for (int u = 0; u < 8; ++u) {
            int jj = j + u;
            s[u] = sbase[jj < last ? jj : last];
        }
        unsigned v[8];
        #pragma unroll
        for (int u = 0; u < 8; ++u)
            v[u] = xu[(size_t)s[u] * 64 + lane];
        #pragma unroll
        for (int u = 0; u < 8; ++u)
            v[u] = (j + u < degc) ? v[u] : 0u;
        #pragma unroll
        for (int u = 0; u < 8; ++u) {
            ax += bflo(v[u]);
            ay += bfhi(v[u]);
        }
    }
    float sc = 1.0f / (float)(deg > 1 ? deg : 1);
    unsigned o = (unsigned)f2bf(ax * sc) | ((unsigned)f2bf(ay * sc) << 16);
    ((unsigned*)(aggh + (size_t)bid * DD))[lane] = o;
}

// ---------------- fused GEMM: out = relu([xh|agg]@QBt^T + cb) @ P2t^T + b2 ----------
// Stage1: 128x128 h-tile via 8 K-chunks (As/Bs in LDS). h -> LDS (bf16).
// Stage2: K=128 fully local: h_tile @ P2 -> out.
// LDS union: stage1 As[128][72]+Bs[128][72] = 36,864 B; stage2 Hs[128][136]+Ps[128][136]
// = 69,632 B  ->  S = 34,816 ushorts (69.6 KB, 2 blocks/CU).
__global__ __launch_bounds__(256) void gemm_fused_kernel(
    const ushort* __restrict__ xh, const ushort* __restrict__ aggh,
    const ushort* __restrict__ QBt, const float* __restrict__ cb,
    const ushort* __restrict__ P2t, const float* __restrict__ b2,
    float* __restrict__ out)
{
    __shared__ ushort S[34816];                        // 69,632 B
    ushort (*As)[72]  = (ushort(*)[72])S;              // stage1 A  [128][72]
    ushort (*Bs)[72]  = (ushort(*)[72])(S + 9216);     // stage1 B  [128][72]
    ushort (*Hs)[136] = (ushort(*)[136])S;             // stage2 A  [128][136]
    ushort (*Ps)[136] = (ushort(*)[136])(S + 17408);   // stage2 B  [128][136]

    int tid = threadIdx.x;
    int n0 = blockIdx.x * 128;
    int wid = tid >> 6;
    int lane = tid & 63;
    int wr = wid >> 1, wc = wid & 1;
    int lrow = lane & 15;
    int lk = (lane >> 4) * 8;

    f32x4 acc[4][4];
    #pragma unroll
    for (int i = 0; i < 4; ++i)
        #pragma unroll
        for (int j = 0; j < 4; ++j) acc[i][j] = (f32x4){0.f, 0.f, 0.f, 0.f};

    for (int c = 0; c < 8; ++c) {
        int seg = c >> 1;
        int kloc = (c & 1) * 64;
        const ushort* Abase = (seg == 0) ? xh : (aggh + (size_t)(seg - 1) * NN * DD);
        if (c) __syncthreads();
        #pragma unroll
        for (int i = 0; i < 4; ++i) {
            int id = tid + i * 256;
            int row = id >> 3;
            int s16 = id & 7;
            int grow = n0 + row;
            ushort8 v = {0, 0, 0, 0, 0, 0, 0, 0};
            if (grow < NN)
                v = *(const ushort8*)(Abase + (size_t)grow * DD + kloc + s16 * 8);
            *(ushort8*)&As[row][s16 * 8] = v;
        }
        #pragma unroll
        for (int i = 0; i < 4; ++i) {
            int id = tid + i * 256;
            int n = id >> 3;
            int s16 = id & 7;
            *(ushort8*)&Bs[n][s16 * 8] =
                *(const ushort8*)(QBt + (size_t)n * 512 + c * 64 + s16 * 8);
        }
        __syncthreads();
        #pragma unroll
        for (int ks = 0; ks < 2; ++ks) {
            bf16x8 a[4], b[4];
            #pragma unroll
            for (int mi = 0; mi < 4; ++mi)
                a[mi] = *(const bf16x8*)&As[wr * 64 + mi * 16 + lrow][ks * 32 + lk];
            #pragma unroll
            for (int ni = 0; ni < 4; ++ni)
                b[ni] = *(const bf16x8*)&Bs[wc * 64 + ni * 16 + lrow][ks * 32 + lk];
            #pragma unroll
            for (int mi = 0; mi < 4; ++mi)
                #pragma unroll
                for (int ni = 0; ni < 4; ++ni)
                    acc[mi][ni] = __builtin_amdgcn_mfma_f32_16x16x32_bf16(
                        a[mi], b[ni], acc[mi][ni], 0, 0, 0);
        }
    }

    __syncthreads();   // all stage1 LDS reads done before repurposing

    // epilogue1: h = relu(acc + cb) -> Hs (bf16); C/D layout row=(lane>>4)*4+q, col=lane&15
    int crow = lane >> 4;
    int ccol = lane & 15;
    #pragma unroll
    for (int ni = 0; ni < 4; ++ni) {
        int gcol = wc * 64 + ni * 16 + ccol;
        float cv = cb[gcol];
        #pragma unroll
        for (int mi = 0; mi < 4; ++mi) {
            #pragma unroll
            for (int q = 0; q < 4; ++q) {
                float v = acc[mi][ni][q] + cv;
                v = v > 0.f ? v : 0.f;
                Hs[wr * 64 + mi * 16 + crow * 4 + q][gcol] = f2bf(v);
            }
        }
    }
    // stage P2t: 128 rows x 128 k (16 ushort8 per row)
    #pragma unroll
    for (int i = 0; i < 8; ++i) {
        int id = tid + i * 256;
        int n = id >> 4, cc = id & 15;
        *(ushort8*)&Ps[n][cc * 8] = *(const ushort8*)(P2t + (size_t)n * DD + cc * 8);
    }
    __syncthreads();

    f32x4 acc2[4][4];
    #pragma unroll
    for (int i = 0; i < 4; ++i)
        #pragma unroll
        for (int j = 0; j < 4; ++j) acc2[i][j] = (f32x4){0.f, 0.f, 0.f, 0.f};

    #pragma unroll
    for (int ks = 0; ks < 4; ++ks) {
        bf16x8 a[4], b[4];
        #pragma unroll
        for (int mi = 0; mi < 4; ++mi)
            a[mi] = *(const bf16x8*)&Hs[wr * 64 + mi * 16 + lrow][ks * 32 + lk];
        #pragma unroll
        for (int ni = 0; ni < 4; ++ni)
            b[ni] = *(const bf16x8*)&Ps[wc * 64 + ni * 16 + lrow][ks * 32 + lk];
        #pragma unroll
        for (int mi = 0; mi < 4; ++mi)
            #pragma unroll
            for (int ni = 0; ni < 4; ++ni)
                acc2[mi][ni] = __builtin_amdgcn_mfma_f32_16x16x32_bf16(
                    a[mi], b[ni], acc2[mi][ni], 0, 0, 0);
    }

    #pragma unroll
    for (int ni = 0; ni < 4; ++ni) {
        int gcol = wc * 64 + ni * 16 + ccol;
        float bv = b2[gcol];
        #pragma unroll
        for (int mi = 0; mi < 4; ++mi) {
            #pragma unroll
            for (int q = 0; q < 4; ++q) {
                int gr = n0 + wr * 64 + mi * 16 + crow * 4 + q;
                if (gr < NN)
                    out[(size_t)gr * DD + gcol] = acc2[mi][ni][q] + bv;
            }
        }
    }
}

extern "C" void kernel_launch(void* const* d_in, const int* in_sizes, int n_in,
                              void* d_out, int out_size, void* d_ws, size_t ws_size,
                              hipStream_t stream) {
    const float* x  = (const float*)d_in[0];
    const int*   e0 = (const int*)d_in[1];
    const int*   e1 = (const int*)d_in[2];
    const int*   e2 = (const int*)d_in[3];
    const float* Wl = (const float*)d_in[4];
    const float* bl = (const float*)d_in[5];
    const float* Wr = (const float*)d_in[6];
    const float* P1 = (const float*)d_in[7];
    const float* b1 = (const float*)d_in[8];
    const float* P2 = (const float*)d_in[9];
    const float* b2 = (const float*)d_in[10];
    float* out = (float*)d_out;

    // ws layout (~142 MB)
    ushort* xh     = (ushort*)d_ws;                       // N*D        (25.6 MB)
    ushort* aggh   = xh + (size_t)NN * DD;                // R*N*D      (76.8 MB)
    ushort* QBt    = aggh + (size_t)RR * NN * DD;         // 128*512
    ushort* P2t    = QBt + (size_t)128 * 512;             // 128*128
    float*  cb     = (float*)(P2t + (size_t)DD * DD);     // D
    int*    cnt    = (int*)(cb + DD);                     // MM         (1.2 MB)
    int*    srcidx = cnt + MM;                            // MM*CAP     (38.4 MB)

    hipMemsetAsync(cnt, 0, (size_t)MM * sizeof(int), stream);

    precompute_qbt_kernel<<<4 * DD, DD, 0, stream>>>(Wl, Wr, P1, QBt);
    precompute_p2t_kernel<<<DD, DD, 0, stream>>>(P2, P2t);
    precompute_c_kernel<<<1, DD, 0, stream>>>(bl, P1, b1, cb);

    x_tobf16_kernel<<<(NN * DD / 4 + 255) / 256, 256, 0, stream>>>(x, xh);

    int eblocks = (RR * EE + 255) / 256;
    fill_kernel<<<eblocks, 256, 0, stream>>>(e0, e1, e2, cnt, srcidx);

    aggregate_kernel<<<MM / 4, 256, 0, stream>>>(xh, srcidx, cnt, aggh);

    int gblocks = (NN + 127) / 128;
    gemm_fused_kernel<<<gblocks, 256, 0, stream>>>(xh, aggh, QBt, cb, P2t, b2, out);
}

// Round 7
// 229.983 us; speedup vs baseline: 6.7644x; 1.2708x over previous
//
#include <hip/hip_runtime.h>
#include <hip/hip_bf16.h>

#define NN 100000
#define DD 128
#define EE 500000
#define RR 3
#define MM (RR * NN)          // total buckets = 300000
#define NBIN 293              // ceil(MM / 1024) coarse bins
#define BCAP 6144             // per-bin capacity (Poisson mean 5120, +14 sigma)

typedef __attribute__((ext_vector_type(8))) short   bf16x8;
typedef __attribute__((ext_vector_type(8))) ushort  ushort8;
typedef __attribute__((ext_vector_type(4))) float   f32x4;

__device__ __forceinline__ ushort f2bf(float f) {
    __hip_bfloat16 h = __float2bfloat16(f);   // RNE
    return *(ushort*)&h;
}
__device__ __forceinline__ float bflo(unsigned v) {
    unsigned u = v << 16;
    return *(float*)&u;
}
__device__ __forceinline__ float bfhi(unsigned v) {
    unsigned u = v & 0xffff0000u;
    return *(float*)&u;
}

// ---------------- precompute fused weights (bf16, transposed) ----------------
// QBt layout: [n=128][k=512]; k = s*128+i; s0 = Qx = sum_r Wr_r@P1_r, s1..3 = Wl_r@P1_r
__global__ __launch_bounds__(128) void precompute_qbt_kernel(
    const float* __restrict__ Wl, const float* __restrict__ Wr,
    const float* __restrict__ P1, ushort* __restrict__ QBt)
{
    int s = blockIdx.x >> 7;   // 0..3
    int i = blockIdx.x & 127;  // k within segment
    int j = threadIdx.x;       // output col n
    float acc = 0.f;
    if (s == 0) {
        for (int r = 0; r < RR; ++r) {
            const float* wrow = Wr + (size_t)(r * DD + i) * DD;
            const float* pcol = P1 + (size_t)(r * DD) * DD + j;
            for (int k = 0; k < DD; ++k)
                acc += wrow[k] * pcol[(size_t)k * DD];
        }
    } else {
        int r = s - 1;
        const float* wrow = Wl + (size_t)(r * DD + i) * DD;
        const float* pcol = P1 + (size_t)(r * DD) * DD + j;
        for (int k = 0; k < DD; ++k)
            acc += wrow[k] * pcol[(size_t)k * DD];
    }
    QBt[(size_t)j * 512 + s * DD + i] = f2bf(acc);
}

__global__ __launch_bounds__(128) void precompute_p2t_kernel(
    const float* __restrict__ P2, ushort* __restrict__ P2t)
{
    int j = blockIdx.x;   // output col
    int k = threadIdx.x;
    P2t[(size_t)j * DD + k] = f2bf(P2[(size_t)k * DD + j]);
}

__global__ __launch_bounds__(128) void precompute_c_kernel(
    const float* __restrict__ bl, const float* __restrict__ P1,
    const float* __restrict__ b1, float* __restrict__ cb)
{
    int j = threadIdx.x;
    float acc = b1[j];
    for (int r = 0; r < RR; ++r)
        for (int k = 0; k < DD; ++k)
            acc += bl[r * DD + k] * P1[(size_t)(r * DD + k) * DD + j];
    cb[j] = acc;
}

// ---------------- x -> bf16 ----------------
__global__ __launch_bounds__(256) void x_tobf16_kernel(
    const float* __restrict__ x, ushort* __restrict__ xh)
{
    size_t i = (size_t)blockIdx.x * 256 + threadIdx.x;   // 4 elems each
    if (i * 4 >= (size_t)NN * DD) return;
    float4 v = ((const float4*)x)[i];
    unsigned lo = (unsigned)f2bf(v.x) | ((unsigned)f2bf(v.y) << 16);
    unsigned hi = (unsigned)f2bf(v.z) | ((unsigned)f2bf(v.w) << 16);
    ((uint2*)xh)[i] = make_uint2(lo, hi);
}

// ---------------- phase A: coarse binning (4096 edges/block) ----------------
// packed word = src | (local << 17);  src < 2^17, local < 2^10
__global__ __launch_bounds__(256) void bin_kernel(
    const int* __restrict__ e0, const int* __restrict__ e1, const int* __restrict__ e2,
    int* __restrict__ g_cursor, int* __restrict__ g_bindata)
{
    __shared__ int hist[NBIN];
    __shared__ int base[NBIN];
    int tid = threadIdx.x;
    for (int i = tid; i < NBIN; i += 256) hist[i] = 0;
    __syncthreads();
    int e_begin = blockIdx.x * 4096;
    int e_end = e_begin + 4096; if (e_end > RR * EE) e_end = RR * EE;
    // pass 1: histogram coarse bins (dst only)
    for (int i = e_begin + tid; i < e_end; i += 256) {
        int r = i / EE, e = i - r * EE;
        const int* ei = (r == 0) ? e0 : (r == 1) ? e1 : e2;
        int bin = (r * NN + ei[EE + e]) >> 10;
        atomicAdd(&hist[bin], 1);
    }
    __syncthreads();
    // reserve global space per bin, reset local cursors
    for (int i = tid; i < NBIN; i += 256) {
        int c = hist[i];
        base[i] = c ? atomicAdd(&g_cursor[i], c) : 0;
        hist[i] = 0;
    }
    __syncthreads();
    // pass 2: scatter packed words into bin segments (block-clustered)
    for (int i = e_begin + tid; i < e_end; i += 256) {
        int r = i / EE, e = i - r * EE;
        const int* ei = (r == 0) ? e0 : (r == 1) ? e1 : e2;
        int src = ei[e];
        int b = r * NN + ei[EE + e];
        int bin = b >> 10, local = b & 1023;
        int slot = base[bin] + atomicAdd(&hist[bin], 1);
        if (slot < BCAP) g_bindata[bin * BCAP + slot] = src | (local << 17);
    }
}

// ---------------- phase B: per-bin local sort -> exact CSR ----------------
__global__ __launch_bounds__(256) void sort_kernel(
    const int* __restrict__ g_cursor, const int* __restrict__ g_bindata,
    int* __restrict__ sorted, int* __restrict__ gStart, int* __restrict__ gDeg)
{
    __shared__ int hist[1024];
    __shared__ int start[1024];
    __shared__ int ssum[256];
    int bin = blockIdx.x, tid = threadIdx.x;
    int cnt = g_cursor[bin]; if (cnt > BCAP) cnt = BCAP;
    const int* bd = g_bindata + bin * BCAP;
    #pragma unroll
    for (int i = tid; i < 1024; i += 256) hist[i] = 0;
    __syncthreads();
    for (int i = tid; i < cnt; i += 256)
        atomicAdd(&hist[bd[i] >> 17], 1);
    __syncthreads();
    // exclusive scan over 1024 (4 per thread + block scan of thread sums)
    int t4 = tid * 4;
    int a0 = hist[t4], a1 = hist[t4 + 1], a2 = hist[t4 + 2], a3 = hist[t4 + 3];
    int ts = a0 + a1 + a2 + a3;
    ssum[tid] = ts;
    __syncthreads();
    #pragma unroll
    for (int off = 1; off < 256; off <<= 1) {
        int tmp = (tid >= off) ? ssum[tid - off] : 0;
        __syncthreads();
        ssum[tid] += tmp;
        __syncthreads();
    }
    int ex = ssum[tid] - ts;
    start[t4] = ex; start[t4 + 1] = ex + a0;
    start[t4 + 2] = ex + a0 + a1; start[t4 + 3] = ex + a0 + a1 + a2;
    __syncthreads();
    // write CSR meta + convert hist -> cursors (same thread per index, then barrier)
    for (int i = tid; i < 1024; i += 256) {
        int bucket = (bin << 10) + i;
        if (bucket < MM) {
            gStart[bucket] = bin * BCAP + start[i];
            gDeg[bucket] = hist[i];
        }
        hist[i] = start[i];
    }
    __syncthreads();
    // scatter srcs bucket-contiguous (writes confined to 24KB L2 window)
    for (int i = tid; i < cnt; i += 256) {
        int w = bd[i];
        int pos = atomicAdd(&hist[w >> 17], 1);
        sorted[bin * BCAP + pos] = w & 0x1ffff;
    }
}

// ---------------- gather-aggregate: predicated unroll-8 for MLP ----------------
__global__ __launch_bounds__(256) void aggregate_kernel(
    const ushort* __restrict__ xh, const int* __restrict__ sorted,
    const int* __restrict__ gStart, const int* __restrict__ gDeg,
    ushort* __restrict__ aggh)
{
    int bid = blockIdx.x * 4 + (threadIdx.x >> 6);   // grid exact: 75000*4 = MM
    int lane = threadIdx.x & 63;
    int deg = gDeg[bid];
    const int* sbase = sorted + gStart[bid];
    const unsigned* xu = (const unsigned*)xh;
    float ax = 0.f, ay = 0.f;
    int last = deg - 1;
    for (int j = 0; j < deg; j += 8) {
        int s[8];
        #pragma unroll
        for (int u = 0; u < 8; ++u) {
            int jj = j + u;
            s[u] = sbase[jj < last ? jj : last];
        }
        unsigned v[8];
        #pragma unroll
        for (int u = 0; u < 8; ++u)
            v[u] = xu[(size_t)s[u] * 64 + lane];
        #pragma unroll
        for (int u = 0; u < 8; ++u)
            v[u] = (j + u < deg) ? v[u] : 0u;
        #pragma unroll
        for (int u = 0; u < 8; ++u) {
            ax += bflo(v[u]);
            ay += bfhi(v[u]);
        }
    }
    float sc = 1.0f / (float)(deg > 1 ? deg : 1);
    unsigned o = (unsigned)f2bf(ax * sc) | ((unsigned)f2bf(ay * sc) << 16);
    ((unsigned*)(aggh + (size_t)bid * DD))[lane] = o;
}

// ---------------- fused GEMM: out = relu([xh|agg]@QBt^T + cb) @ P2t^T + b2 ----------
// Stage1: 128x128 h-tile via 8 K-chunks (As/Bs in LDS). h -> LDS (bf16).
// Stage2: K=128 fully local: h_tile @ P2 -> out.
// LDS union: stage1 As[128][72]+Bs[128][72] = 36,864 B; stage2 Hs[128][136]+Ps[128][136]
// = 69,632 B  ->  S = 34,816 ushorts (69.6 KB, 2 blocks/CU).
__global__ __launch_bounds__(256) void gemm_fused_kernel(
    const ushort* __restrict__ xh, const ushort* __restrict__ aggh,
    const ushort* __restrict__ QBt, const float* __restrict__ cb,
    const ushort* __restrict__ P2t, const float* __restrict__ b2,
    float* __restrict__ out)
{
    __shared__ ushort S[34816];                        // 69,632 B
    ushort (*As)[72]  = (ushort(*)[72])S;              // stage1 A  [128][72]
    ushort (*Bs)[72]  = (ushort(*)[72])(S + 9216);     // stage1 B  [128][72]
    ushort (*Hs)[136] = (ushort(*)[136])S;             // stage2 A  [128][136]
    ushort (*Ps)[136] = (ushort(*)[136])(S + 17408);   // stage2 B  [128][136]

    int tid = threadIdx.x;
    int n0 = blockIdx.x * 128;
    int wid = tid >> 6;
    int lane = tid & 63;
    int wr = wid >> 1, wc = wid & 1;
    int lrow = lane & 15;
    int lk = (lane >> 4) * 8;

    f32x4 acc[4][4];
    #pragma unroll
    for (int i = 0; i < 4; ++i)
        #pragma unroll
        for (int j = 0; j < 4; ++j) acc[i][j] = (f32x4){0.f, 0.f, 0.f, 0.f};

    for (int c = 0; c < 8; ++c) {
        int seg = c >> 1;
        int kloc = (c & 1) * 64;
        const ushort* Abase = (seg == 0) ? xh : (aggh + (size_t)(seg - 1) * NN * DD);
        if (c) __syncthreads();
        #pragma unroll
        for (int i = 0; i < 4; ++i) {
            int id = tid + i * 256;
            int row = id >> 3;
            int s16 = id & 7;
            int grow = n0 + row;
            ushort8 v = {0, 0, 0, 0, 0, 0, 0, 0};
            if (grow < NN)
                v = *(const ushort8*)(Abase + (size_t)grow * DD + kloc + s16 * 8);
            *(ushort8*)&As[row][s16 * 8] = v;
        }
        #pragma unroll
        for (int i = 0; i < 4; ++i) {
            int id = tid + i * 256;
            int n = id >> 3;
            int s16 = id & 7;
            *(ushort8*)&Bs[n][s16 * 8] =
                *(const ushort8*)(QBt + (size_t)n * 512 + c * 64 + s16 * 8);
        }
        __syncthreads();
        #pragma unroll
        for (int ks = 0; ks < 2; ++ks) {
            bf16x8 a[4], b[4];
            #pragma unroll
            for (int mi = 0; mi < 4; ++mi)
                a[mi] = *(const bf16x8*)&As[wr * 64 + mi * 16 + lrow][ks * 32 + lk];
            #pragma unroll
            for (int ni = 0; ni < 4; ++ni)
                b[ni] = *(const bf16x8*)&Bs[wc * 64 + ni * 16 + lrow][ks * 32 + lk];
            #pragma unroll
            for (int mi = 0; mi < 4; ++mi)
                #pragma unroll
                for (int ni = 0; ni < 4; ++ni)
                    acc[mi][ni] = __builtin_amdgcn_mfma_f32_16x16x32_bf16(
                        a[mi], b[ni], acc[mi][ni], 0, 0, 0);
        }
    }

    __syncthreads();   // all stage1 LDS reads done before repurposing

    // epilogue1: h = relu(acc + cb) -> Hs (bf16); C/D layout row=(lane>>4)*4+q, col=lane&15
    int crow = lane >> 4;
    int ccol = lane & 15;
    #pragma unroll
    for (int ni = 0; ni < 4; ++ni) {
        int gcol = wc * 64 + ni * 16 + ccol;
        float cv = cb[gcol];
        #pragma unroll
        for (int mi = 0; mi < 4; ++mi) {
            #pragma unroll
            for (int q = 0; q < 4; ++q) {
                float v = acc[mi][ni][q] + cv;
                v = v > 0.f ? v : 0.f;
                Hs[wr * 64 + mi * 16 + crow * 4 + q][gcol] = f2bf(v);
            }
        }
    }
    // stage P2t: 128 rows x 128 k (16 ushort8 per row)
    #pragma unroll
    for (int i = 0; i < 8; ++i) {
        int id = tid + i * 256;
        int n = id >> 4, cc = id & 15;
        *(ushort8*)&Ps[n][cc * 8] = *(const ushort8*)(P2t + (size_t)n * DD + cc * 8);
    }
    __syncthreads();

    f32x4 acc2[4][4];
    #pragma unroll
    for (int i = 0; i < 4; ++i)
        #pragma unroll
        for (int j = 0; j < 4; ++j) acc2[i][j] = (f32x4){0.f, 0.f, 0.f, 0.f};

    #pragma unroll
    for (int ks = 0; ks < 4; ++ks) {
        bf16x8 a[4], b[4];
        #pragma unroll
        for (int mi = 0; mi < 4; ++mi)
            a[mi] = *(const bf16x8*)&Hs[wr * 64 + mi * 16 + lrow][ks * 32 + lk];
        #pragma unroll
        for (int ni = 0; ni < 4; ++ni)
            b[ni] = *(const bf16x8*)&Ps[wc * 64 + ni * 16 + lrow][ks * 32 + lk];
        #pragma unroll
        for (int mi = 0; mi < 4; ++mi)
            #pragma unroll
            for (int ni = 0; ni < 4; ++ni)
                acc2[mi][ni] = __builtin_amdgcn_mfma_f32_16x16x32_bf16(
                    a[mi], b[ni], acc2[mi][ni], 0, 0, 0);
    }

    #pragma unroll
    for (int ni = 0; ni < 4; ++ni) {
        int gcol = wc * 64 + ni * 16 + ccol;
        float bv = b2[gcol];
        #pragma unroll
        for (int mi = 0; mi < 4; ++mi) {
            #pragma unroll
            for (int q = 0; q < 4; ++q) {
                int gr = n0 + wr * 64 + mi * 16 + crow * 4 + q;
                if (gr < NN)
                    out[(size_t)gr * DD + gcol] = acc2[mi][ni][q] + bv;
            }
        }
    }
}

extern "C" void kernel_launch(void* const* d_in, const int* in_sizes, int n_in,
                              void* d_out, int out_size, void* d_ws, size_t ws_size,
                              hipStream_t stream) {
    const float* x  = (const float*)d_in[0];
    const int*   e0 = (const int*)d_in[1];
    const int*   e1 = (const int*)d_in[2];
    const int*   e2 = (const int*)d_in[3];
    const float* Wl = (const float*)d_in[4];
    const float* bl = (const float*)d_in[5];
    const float* Wr = (const float*)d_in[6];
    const float* P1 = (const float*)d_in[7];
    const float* b1 = (const float*)d_in[8];
    const float* P2 = (const float*)d_in[9];
    const float* b2 = (const float*)d_in[10];
    float* out = (float*)d_out;

    // ws layout (~122 MB)
    ushort* xh       = (ushort*)d_ws;                     // N*D        (25.6 MB)
    ushort* aggh     = xh + (size_t)NN * DD;              // R*N*D      (76.8 MB)
    ushort* QBt      = aggh + (size_t)RR * NN * DD;       // 128*512
    ushort* P2t      = QBt + (size_t)128 * 512;           // 128*128
    float*  cb       = (float*)(P2t + (size_t)DD * DD);   // D
    int*    g_cursor = (int*)(cb + DD);                   // NBIN
    int*    g_bindat = g_cursor + NBIN;                   // NBIN*BCAP  (7.2 MB)
    int*    sorted   = g_bindat + (size_t)NBIN * BCAP;    // NBIN*BCAP  (7.2 MB)
    int*    gStart   = sorted + (size_t)NBIN * BCAP;      // MM
    int*    gDeg     = gStart + MM;                       // MM

    hipMemsetAsync(g_cursor, 0, NBIN * sizeof(int), stream);

    precompute_qbt_kernel<<<4 * DD, DD, 0, stream>>>(Wl, Wr, P1, QBt);
    precompute_p2t_kernel<<<DD, DD, 0, stream>>>(P2, P2t);
    precompute_c_kernel<<<1, DD, 0, stream>>>(bl, P1, b1, cb);

    x_tobf16_kernel<<<(NN * DD / 4 + 255) / 256, 256, 0, stream>>>(x, xh);

    int ablocks = (RR * EE + 4095) / 4096;   // 367
    bin_kernel<<<ablocks, 256, 0, stream>>>(e0, e1, e2, g_cursor, g_bindat);

    sort_kernel<<<NBIN, 256, 0, stream>>>(g_cursor, g_bindat, sorted, gStart, gDeg);

    aggregate_kernel<<<MM / 4, 256, 0, stream>>>(xh, sorted, gStart, gDeg, aggh);

    int gblocks = (NN + 127) / 128;
    gemm_fused_kernel<<<gblocks, 256, 0, stream>>>(xh, aggh, QBt, cb, P2t, b2, out);
}

// Round 8
// 223.545 us; speedup vs baseline: 6.9592x; 1.0288x over previous
//
#include <hip/hip_runtime.h>
#include <hip/hip_bf16.h>

#define NN 100000
#define DD 128
#define EE 500000
#define RR 3
#define MM (RR * NN)          // total buckets = 300000
#define NBIN 293              // ceil(MM / 1024) coarse bins
#define BCAP_RAW 6144         // per-bin raw capacity (Poisson mean 5120, +14 sigma)
#define BCAP_PAD 10240        // per-bin padded capacity (mean ~8700, ~19 sigma)

typedef __attribute__((ext_vector_type(8))) short   bf16x8;
typedef __attribute__((ext_vector_type(8))) ushort  ushort8;
typedef __attribute__((ext_vector_type(4))) float   f32x4;

__device__ __forceinline__ ushort f2bf(float f) {
    __hip_bfloat16 h = __float2bfloat16(f);   // RNE
    return *(ushort*)&h;
}
__device__ __forceinline__ float bflo(unsigned v) {
    unsigned u = v << 16;
    return *(float*)&u;
}
__device__ __forceinline__ float bfhi(unsigned v) {
    unsigned u = v & 0xffff0000u;
    return *(float*)&u;
}

// ---------------- precompute fused weights (bf16, transposed) ----------------
// QBt layout: [n=128][k=512]; k = s*128+i; s0 = Qx = sum_r Wr_r@P1_r, s1..3 = Wl_r@P1_r
__global__ __launch_bounds__(128) void precompute_qbt_kernel(
    const float* __restrict__ Wl, const float* __restrict__ Wr,
    const float* __restrict__ P1, ushort* __restrict__ QBt)
{
    int s = blockIdx.x >> 7;   // 0..3
    int i = blockIdx.x & 127;  // k within segment
    int j = threadIdx.x;       // output col n
    float acc = 0.f;
    if (s == 0) {
        for (int r = 0; r < RR; ++r) {
            const float* wrow = Wr + (size_t)(r * DD + i) * DD;
            const float* pcol = P1 + (size_t)(r * DD) * DD + j;
            for (int k = 0; k < DD; ++k)
                acc += wrow[k] * pcol[(size_t)k * DD];
        }
    } else {
        int r = s - 1;
        const float* wrow = Wl + (size_t)(r * DD + i) * DD;
        const float* pcol = P1 + (size_t)(r * DD) * DD + j;
        for (int k = 0; k < DD; ++k)
            acc += wrow[k] * pcol[(size_t)k * DD];
    }
    QBt[(size_t)j * 512 + s * DD + i] = f2bf(acc);
}

__global__ __launch_bounds__(128) void precompute_p2t_kernel(
    const float* __restrict__ P2, ushort* __restrict__ P2t)
{
    int j = blockIdx.x;   // output col
    int k = threadIdx.x;
    P2t[(size_t)j * DD + k] = f2bf(P2[(size_t)k * DD + j]);
}

__global__ __launch_bounds__(128) void precompute_c_kernel(
    const float* __restrict__ bl, const float* __restrict__ P1,
    const float* __restrict__ b1, float* __restrict__ cb)
{
    int j = threadIdx.x;
    float acc = b1[j];
    for (int r = 0; r < RR; ++r)
        for (int k = 0; k < DD; ++k)
            acc += bl[r * DD + k] * P1[(size_t)(r * DD + k) * DD + j];
    cb[j] = acc;
}

// ---------------- x -> bf16 ----------------
__global__ __launch_bounds__(256) void x_tobf16_kernel(
    const float* __restrict__ x, ushort* __restrict__ xh)
{
    size_t i = (size_t)blockIdx.x * 256 + threadIdx.x;   // 4 elems each
    if (i * 4 >= (size_t)NN * DD) return;
    float4 v = ((const float4*)x)[i];
    unsigned lo = (unsigned)f2bf(v.x) | ((unsigned)f2bf(v.y) << 16);
    unsigned hi = (unsigned)f2bf(v.z) | ((unsigned)f2bf(v.w) << 16);
    ((uint2*)xh)[i] = make_uint2(lo, hi);
}

// ---------------- phase A: coarse binning (4096 edges/block) ----------------
// packed word = src | (local << 17);  src < 2^17, local < 2^10
__global__ __launch_bounds__(256) void bin_kernel(
    const int* __restrict__ e0, const int* __restrict__ e1, const int* __restrict__ e2,
    int* __restrict__ g_cursor, int* __restrict__ g_bindata)
{
    __shared__ int hist[NBIN];
    __shared__ int base[NBIN];
    int tid = threadIdx.x;
    for (int i = tid; i < NBIN; i += 256) hist[i] = 0;
    __syncthreads();
    int e_begin = blockIdx.x * 4096;
    int e_end = e_begin + 4096; if (e_end > RR * EE) e_end = RR * EE;
    // pass 1: histogram coarse bins (dst only)
    for (int i = e_begin + tid; i < e_end; i += 256) {
        int r = i / EE, e = i - r * EE;
        const int* ei = (r == 0) ? e0 : (r == 1) ? e1 : e2;
        int bin = (r * NN + ei[EE + e]) >> 10;
        atomicAdd(&hist[bin], 1);
    }
    __syncthreads();
    // reserve global space per bin, reset local cursors
    for (int i = tid; i < NBIN; i += 256) {
        int c = hist[i];
        base[i] = c ? atomicAdd(&g_cursor[i], c) : 0;
        hist[i] = 0;
    }
    __syncthreads();
    // pass 2: scatter packed words into bin segments (block-clustered)
    for (int i = e_begin + tid; i < e_end; i += 256) {
        int r = i / EE, e = i - r * EE;
        const int* ei = (r == 0) ? e0 : (r == 1) ? e1 : e2;
        int src = ei[e];
        int b = r * NN + ei[EE + e];
        int bin = b >> 10, local = b & 1023;
        int slot = base[bin] + atomicAdd(&hist[bin], 1);
        if (slot < BCAP_RAW) g_bindata[(size_t)bin * BCAP_RAW + slot] = src | (local << 17);
    }
}

// ---------------- phase B: per-bin local sort -> exact CSR, 8-padded ----------------
// bucket segments padded to multiple of 8 with src = NN (zero row of xh)
__global__ __launch_bounds__(256) void sort_kernel(
    const int* __restrict__ g_cursor, const int* __restrict__ g_bindata,
    int* __restrict__ sorted, int* __restrict__ gStart, int* __restrict__ gDeg)
{
    __shared__ int hist[1024];
    __shared__ int start[1024];
    __shared__ int ssum[256];
    int bin = blockIdx.x, tid = threadIdx.x;
    int cnt = g_cursor[bin]; if (cnt > BCAP_RAW) cnt = BCAP_RAW;
    const int* bd = g_bindata + (size_t)bin * BCAP_RAW;
    for (int i = tid; i < 1024; i += 256) hist[i] = 0;
    __syncthreads();
    for (int i = tid; i < cnt; i += 256)
        atomicAdd(&hist[bd[i] >> 17], 1);
    __syncthreads();
    // exclusive scan over PADDED lengths (4 per thread + block scan)
    int t4 = tid * 4;
    int a0 = hist[t4], a1 = hist[t4 + 1], a2 = hist[t4 + 2], a3 = hist[t4 + 3];
    int p0 = (a0 + 7) & ~7, p1 = (a1 + 7) & ~7, p2 = (a2 + 7) & ~7, p3 = (a3 + 7) & ~7;
    int ts = p0 + p1 + p2 + p3;
    ssum[tid] = ts;
    __syncthreads();
    #pragma unroll
    for (int off = 1; off < 256; off <<= 1) {
        int tmp = (tid >= off) ? ssum[tid - off] : 0;
        __syncthreads();
        ssum[tid] += tmp;
        __syncthreads();
    }
    int ex = ssum[tid] - ts;
    start[t4] = ex; start[t4 + 1] = ex + p0;
    start[t4 + 2] = ex + p0 + p1; start[t4 + 3] = ex + p0 + p1 + p2;
    __syncthreads();
    // CSR meta + convert hist -> cursors
    for (int i = tid; i < 1024; i += 256) {
        int bucket = (bin << 10) + i;
        if (bucket < MM) {
            gStart[bucket] = bin * BCAP_PAD + start[i];
            gDeg[bucket] = hist[i];
        }
        hist[i] = start[i];
    }
    __syncthreads();
    int* sb = sorted + (size_t)bin * BCAP_PAD;
    // scatter srcs bucket-contiguous (writes confined to L2-resident window)
    for (int i = tid; i < cnt; i += 256) {
        int w = bd[i];
        int pos = atomicAdd(&hist[w >> 17], 1);
        if (pos < BCAP_PAD) sb[pos] = w & 0x1ffff;
    }
    __syncthreads();
    // pad fill: positions [start+d, start+padlen) get zero-row index NN
    for (int i = tid; i < 1024; i += 256) {
        int s0 = start[i];
        int d = hist[i] - s0;              // final cursor - start = raw count
        int pl = (d + 7) & ~7;
        for (int p = s0 + d; p < s0 + pl; ++p)
            if (p < BCAP_PAD) sb[p] = NN;
    }
}

// ---------------- gather-aggregate: readlane SGPR-base gather, padded ----------------
__global__ __launch_bounds__(256) void aggregate_kernel(
    const ushort* __restrict__ xh, const int* __restrict__ sorted,
    const int* __restrict__ gStart, const int* __restrict__ gDeg,
    ushort* __restrict__ aggh)
{
    int bid = blockIdx.x * 4 + (threadIdx.x >> 6);   // grid exact: 75000*4 = MM
    int lane = threadIdx.x & 63;
    int deg = gDeg[bid];
    int degp = (deg + 7) & ~7;                       // padded length (pads = zero row)
    const int* sbase = sorted + gStart[bid];
    const unsigned* xu = (const unsigned*)xh;
    float ax = 0.f, ay = 0.f;
    if (degp <= 64) {
        // all neighbor indices live in one per-lane preload; broadcast via v_readlane
        int sidx = sbase[lane < degp ? lane : 0];
        for (int j = 0; j < degp; j += 8) {
            #pragma unroll
            for (int u = 0; u < 8; ++u) {
                int sj = __builtin_amdgcn_readlane(sidx, j + u);   // SGPR row index
                unsigned v = xu[(size_t)sj * 64 + lane];           // SGPR-base gather
                ax += bflo(v);
                ay += bfhi(v);
            }
        }
    } else {
        for (int j = 0; j < degp; j += 8) {
            #pragma unroll
            for (int u = 0; u < 8; ++u) {
                int sj = sbase[j + u];                // padded: always valid
                unsigned v = xu[(size_t)sj * 64 + lane];
                ax += bflo(v);
                ay += bfhi(v);
            }
        }
    }
    float sc = 1.0f / (float)(deg > 1 ? deg : 1);
    unsigned o = (unsigned)f2bf(ax * sc) | ((unsigned)f2bf(ay * sc) << 16);
    ((unsigned*)(aggh + (size_t)bid * DD))[lane] = o;
}

// ---------------- fused GEMM: out = relu([xh|agg]@QBt^T + cb) @ P2t^T + b2 ----------
// Stage1: 128x128 h-tile via 8 K-chunks (As/Bs in LDS). h -> LDS (bf16).
// Stage2: K=128 fully local: h_tile @ P2 -> out.
// LDS union: stage1 As[128][72]+Bs[128][72] = 36,864 B; stage2 Hs[128][136]+Ps[128][136]
// = 69,632 B  ->  S = 34,816 ushorts (69.6 KB, 2 blocks/CU).
__global__ __launch_bounds__(256) void gemm_fused_kernel(
    const ushort* __restrict__ xh, const ushort* __restrict__ aggh,
    const ushort* __restrict__ QBt, const float* __restrict__ cb,
    const ushort* __restrict__ P2t, const float* __restrict__ b2,
    float* __restrict__ out)
{
    __shared__ ushort S[34816];                        // 69,632 B
    ushort (*As)[72]  = (ushort(*)[72])S;              // stage1 A  [128][72]
    ushort (*Bs)[72]  = (ushort(*)[72])(S + 9216);     // stage1 B  [128][72]
    ushort (*Hs)[136] = (ushort(*)[136])S;             // stage2 A  [128][136]
    ushort (*Ps)[136] = (ushort(*)[136])(S + 17408);   // stage2 B  [128][136]

    int tid = threadIdx.x;
    int n0 = blockIdx.x * 128;
    int wid = tid >> 6;
    int lane = tid & 63;
    int wr = wid >> 1, wc = wid & 1;
    int lrow = lane & 15;
    int lk = (lane >> 4) * 8;

    f32x4 acc[4][4];
    #pragma unroll
    for (int i = 0; i < 4; ++i)
        #pragma unroll
        for (int j = 0; j < 4; ++j) acc[i][j] = (f32x4){0.f, 0.f, 0.f, 0.f};

    for (int c = 0; c < 8; ++c) {
        int seg = c >> 1;
        int kloc = (c & 1) * 64;
        const ushort* Abase = (seg == 0) ? xh : (aggh + (size_t)(seg - 1) * NN * DD);
        if (c) __syncthreads();
        #pragma unroll
        for (int i = 0; i < 4; ++i) {
            int id = tid + i * 256;
            int row = id >> 3;
            int s16 = id & 7;
            int grow = n0 + row;
            ushort8 v = {0, 0, 0, 0, 0, 0, 0, 0};
            if (grow < NN)
                v = *(const ushort8*)(Abase + (size_t)grow * DD + kloc + s16 * 8);
            *(ushort8*)&As[row][s16 * 8] = v;
        }
        #pragma unroll
        for (int i = 0; i < 4; ++i) {
            int id = tid + i * 256;
            int n = id >> 3;
            int s16 = id & 7;
            *(ushort8*)&Bs[n][s16 * 8] =
                *(const ushort8*)(QBt + (size_t)n * 512 + c * 64 + s16 * 8);
        }
        __syncthreads();
        #pragma unroll
        for (int ks = 0; ks < 2; ++ks) {
            bf16x8 a[4], b[4];
            #pragma unroll
            for (int mi = 0; mi < 4; ++mi)
                a[mi] = *(const bf16x8*)&As[wr * 64 + mi * 16 + lrow][ks * 32 + lk];
            #pragma unroll
            for (int ni = 0; ni < 4; ++ni)
                b[ni] = *(const bf16x8*)&Bs[wc * 64 + ni * 16 + lrow][ks * 32 + lk];
            #pragma unroll
            for (int mi = 0; mi < 4; ++mi)
                #pragma unroll
                for (int ni = 0; ni < 4; ++ni)
                    acc[mi][ni] = __builtin_amdgcn_mfma_f32_16x16x32_bf16(
                        a[mi], b[ni], acc[mi][ni], 0, 0, 0);
        }
    }

    __syncthreads();   // all stage1 LDS reads done before repurposing

    // epilogue1: h = relu(acc + cb) -> Hs (bf16); C/D layout row=(lane>>4)*4+q, col=lane&15
    int crow = lane >> 4;
    int ccol = lane & 15;
    #pragma unroll
    for (int ni = 0; ni < 4; ++ni) {
        int gcol = wc * 64 + ni * 16 + ccol;
        float cv = cb[gcol];
        #pragma unroll
        for (int mi = 0; mi < 4; ++mi) {
            #pragma unroll
            for (int q = 0; q < 4; ++q) {
                float v = acc[mi][ni][q] + cv;
                v = v > 0.f ? v : 0.f;
                Hs[wr * 64 + mi * 16 + crow * 4 + q][gcol] = f2bf(v);
            }
        }
    }
    // stage P2t: 128 rows x 128 k (16 ushort8 per row)
    #pragma unroll
    for (int i = 0; i < 8; ++i) {
        int id = tid + i * 256;
        int n = id >> 4, cc = id & 15;
        *(ushort8*)&Ps[n][cc * 8] = *(const ushort8*)(P2t + (size_t)n * DD + cc * 8);
    }
    __syncthreads();

    f32x4 acc2[4][4];
    #pragma unroll
    for (int i = 0; i < 4; ++i)
        #pragma unroll
        for (int j = 0; j < 4; ++j) acc2[i][j] = (f32x4){0.f, 0.f, 0.f, 0.f};

    #pragma unroll
    for (int ks = 0; ks < 4; ++ks) {
        bf16x8 a[4], b[4];
        #pragma unroll
        for (int mi = 0; mi < 4; ++mi)
            a[mi] = *(const bf16x8*)&Hs[wr * 64 + mi * 16 + lrow][ks * 32 + lk];
        #pragma unroll
        for (int ni = 0; ni < 4; ++ni)
            b[ni] = *(const bf16x8*)&Ps[wc * 64 + ni * 16 + lrow][ks * 32 + lk];
        #pragma unroll
        for (int mi = 0; mi < 4; ++mi)
            #pragma unroll
            for (int ni = 0; ni < 4; ++ni)
                acc2[mi][ni] = __builtin_amdgcn_mfma_f32_16x16x32_bf16(
                    a[mi], b[ni], acc2[mi][ni], 0, 0, 0);
    }

    #pragma unroll
    for (int ni = 0; ni < 4; ++ni) {
        int gcol = wc * 64 + ni * 16 + ccol;
        float bv = b2[gcol];
        #pragma unroll
        for (int mi = 0; mi < 4; ++mi) {
            #pragma unroll
            for (int q = 0; q < 4; ++q) {
                int gr = n0 + wr * 64 + mi * 16 + crow * 4 + q;
                if (gr < NN)
                    out[(size_t)gr * DD + gcol] = acc2[mi][ni][q] + bv;
            }
        }
    }
}

extern "C" void kernel_launch(void* const* d_in, const int* in_sizes, int n_in,
                              void* d_out, int out_size, void* d_ws, size_t ws_size,
                              hipStream_t stream) {
    const float* x  = (const float*)d_in[0];
    const int*   e0 = (const int*)d_in[1];
    const int*   e1 = (const int*)d_in[2];
    const int*   e2 = (const int*)d_in[3];
    const float* Wl = (const float*)d_in[4];
    const float* bl = (const float*)d_in[5];
    const float* Wr = (const float*)d_in[6];
    const float* P1 = (const float*)d_in[7];
    const float* b1 = (const float*)d_in[8];
    const float* P2 = (const float*)d_in[9];
    const float* b2 = (const float*)d_in[10];
    float* out = (float*)d_out;

    // ws layout (~124 MB)
    ushort* xh       = (ushort*)d_ws;                     // (N+1)*D    (25.6 MB; row N = zeros)
    ushort* aggh     = xh + (size_t)(NN + 1) * DD;        // R*N*D      (76.8 MB)
    ushort* QBt      = aggh + (size_t)RR * NN * DD;       // 128*512
    ushort* P2t      = QBt + (size_t)128 * 512;           // 128*128
    float*  cb       = (float*)(P2t + (size_t)DD * DD);   // D
    int*    g_cursor = (int*)(cb + DD);                   // NBIN
    int*    g_bindat = g_cursor + NBIN;                   // NBIN*BCAP_RAW (7.2 MB)
    int*    sorted   = g_bindat + (size_t)NBIN * BCAP_RAW;// NBIN*BCAP_PAD + 64 slack (12 MB)
    int*    gStart   = sorted + (size_t)NBIN * BCAP_PAD + 64;  // MM
    int*    gDeg     = gStart + MM;                       // MM

    hipMemsetAsync(g_cursor, 0, NBIN * sizeof(int), stream);
    hipMemsetAsync(xh + (size_t)NN * DD, 0, DD * sizeof(ushort), stream);  // zero row

    precompute_qbt_kernel<<<4 * DD, DD, 0, stream>>>(Wl, Wr, P1, QBt);
    precompute_p2t_kernel<<<DD, DD, 0, stream>>>(P2, P2t);
    precompute_c_kernel<<<1, DD, 0, stream>>>(bl, P1, b1, cb);

    x_tobf16_kernel<<<(NN * DD / 4 + 255) / 256, 256, 0, stream>>>(x, xh);

    int ablocks = (RR * EE + 4095) / 4096;   // 367
    bin_kernel<<<ablocks, 256, 0, stream>>>(e0, e1, e2, g_cursor, g_bindat);

    sort_kernel<<<NBIN, 256, 0, stream>>>(g_cursor, g_bindat, sorted, gStart, gDeg);

    aggregate_kernel<<<MM / 4, 256, 0, stream>>>(xh, sorted, gStart, gDeg, aggh);

    int gblocks = (NN + 127) / 128;
    gemm_fused_kernel<<<gblocks, 256, 0, stream>>>(xh, aggh, QBt, cb, P2t, b2, out);
}

// Round 9
// 209.743 us; speedup vs baseline: 7.4172x; 1.0658x over previous
//
#include <hip/hip_runtime.h>
#include <hip/hip_bf16.h>

#define NN 100000
#define DD 128
#define EE 500000
#define RR 3
#define MM (RR * NN)          // total buckets = 300000
#define NBIN 293              // ceil(MM / 1024) coarse bins
#define BCAP_RAW 6144         // per-bin raw capacity (Poisson mean 5120, +14 sigma)
#define BCAP_PAD 10240        // per-bin padded capacity (mean ~8700, ~19 sigma)

typedef __attribute__((ext_vector_type(8))) short   bf16x8;
typedef __attribute__((ext_vector_type(8))) ushort  ushort8;
typedef __attribute__((ext_vector_type(4))) float   f32x4;

__device__ __forceinline__ ushort f2bf(float f) {
    __hip_bfloat16 h = __float2bfloat16(f);   // RNE
    return *(ushort*)&h;
}
__device__ __forceinline__ float bflo(unsigned v) {
    unsigned u = v << 16;
    return *(float*)&u;
}
__device__ __forceinline__ float bfhi(unsigned v) {
    unsigned u = v & 0xffff0000u;
    return *(float*)&u;
}

// ---------------- precompute fused weights (bf16, transposed) ----------------
// QBt layout: [n=128][k=512]; k = s*128+i; s0 = Qx = sum_r Wr_r@P1_r, s1..3 = Wl_r@P1_r
__global__ __launch_bounds__(128) void precompute_qbt_kernel(
    const float* __restrict__ Wl, const float* __restrict__ Wr,
    const float* __restrict__ P1, ushort* __restrict__ QBt)
{
    int s = blockIdx.x >> 7;   // 0..3
    int i = blockIdx.x & 127;  // k within segment
    int j = threadIdx.x;       // output col n
    float acc = 0.f;
    if (s == 0) {
        for (int r = 0; r < RR; ++r) {
            const float* wrow = Wr + (size_t)(r * DD + i) * DD;
            const float* pcol = P1 + (size_t)(r * DD) * DD + j;
            for (int k = 0; k < DD; ++k)
                acc += wrow[k] * pcol[(size_t)k * DD];
        }
    } else {
        int r = s - 1;
        const float* wrow = Wl + (size_t)(r * DD + i) * DD;
        const float* pcol = P1 + (size_t)(r * DD) * DD + j;
        for (int k = 0; k < DD; ++k)
            acc += wrow[k] * pcol[(size_t)k * DD];
    }
    QBt[(size_t)j * 512 + s * DD + i] = f2bf(acc);
}

__global__ __launch_bounds__(128) void precompute_p2t_kernel(
    const float* __restrict__ P2, ushort* __restrict__ P2t)
{
    int j = blockIdx.x;   // output col
    int k = threadIdx.x;
    P2t[(size_t)j * DD + k] = f2bf(P2[(size_t)k * DD + j]);
}

__global__ __launch_bounds__(128) void precompute_c_kernel(
    const float* __restrict__ bl, const float* __restrict__ P1,
    const float* __restrict__ b1, float* __restrict__ cb)
{
    int j = threadIdx.x;
    float acc = b1[j];
    for (int r = 0; r < RR; ++r)
        for (int k = 0; k < DD; ++k)
            acc += bl[r * DD + k] * P1[(size_t)(r * DD + k) * DD + j];
    cb[j] = acc;
}

// ---------------- x -> bf16 ----------------
__global__ __launch_bounds__(256) void x_tobf16_kernel(
    const float* __restrict__ x, ushort* __restrict__ xh)
{
    size_t i = (size_t)blockIdx.x * 256 + threadIdx.x;   // 4 elems each
    if (i * 4 >= (size_t)NN * DD) return;
    float4 v = ((const float4*)x)[i];
    unsigned lo = (unsigned)f2bf(v.x) | ((unsigned)f2bf(v.y) << 16);
    unsigned hi = (unsigned)f2bf(v.z) | ((unsigned)f2bf(v.w) << 16);
    ((uint2*)xh)[i] = make_uint2(lo, hi);
}

// ---------------- phase A: coarse binning (4096 edges/block) ----------------
// packed word = src | (local << 17);  src < 2^17, local < 2^10
__global__ __launch_bounds__(256) void bin_kernel(
    const int* __restrict__ e0, const int* __restrict__ e1, const int* __restrict__ e2,
    int* __restrict__ g_cursor, int* __restrict__ g_bindata)
{
    __shared__ int hist[NBIN];
    __shared__ int base[NBIN];
    int tid = threadIdx.x;
    for (int i = tid; i < NBIN; i += 256) hist[i] = 0;
    __syncthreads();
    int e_begin = blockIdx.x * 4096;
    int e_end = e_begin + 4096; if (e_end > RR * EE) e_end = RR * EE;
    // pass 1: histogram coarse bins (dst only)
    for (int i = e_begin + tid; i < e_end; i += 256) {
        int r = i / EE, e = i - r * EE;
        const int* ei = (r == 0) ? e0 : (r == 1) ? e1 : e2;
        int bin = (r * NN + ei[EE + e]) >> 10;
        atomicAdd(&hist[bin], 1);
    }
    __syncthreads();
    // reserve global space per bin, reset local cursors
    for (int i = tid; i < NBIN; i += 256) {
        int c = hist[i];
        base[i] = c ? atomicAdd(&g_cursor[i], c) : 0;
        hist[i] = 0;
    }
    __syncthreads();
    // pass 2: scatter packed words into bin segments (block-clustered)
    for (int i = e_begin + tid; i < e_end; i += 256) {
        int r = i / EE, e = i - r * EE;
        const int* ei = (r == 0) ? e0 : (r == 1) ? e1 : e2;
        int src = ei[e];
        int b = r * NN + ei[EE + e];
        int bin = b >> 10, local = b & 1023;
        int slot = base[bin] + atomicAdd(&hist[bin], 1);
        if (slot < BCAP_RAW) g_bindata[(size_t)bin * BCAP_RAW + slot] = src | (local << 17);
    }
}

// ---------------- phase B: per-bin local sort -> exact CSR, 8-padded ----------------
// bucket segments padded to multiple of 8 with src = NN (zero row of xh)
// meta[bucket] = {global start, raw deg}
__global__ __launch_bounds__(256) void sort_kernel(
    const int* __restrict__ g_cursor, const int* __restrict__ g_bindata,
    int* __restrict__ sorted, uint2* __restrict__ meta)
{
    __shared__ int hist[1024];
    __shared__ int start[1024];
    __shared__ int ssum[256];
    int bin = blockIdx.x, tid = threadIdx.x;
    int cnt = g_cursor[bin]; if (cnt > BCAP_RAW) cnt = BCAP_RAW;
    const int* bd = g_bindata + (size_t)bin * BCAP_RAW;
    for (int i = tid; i < 1024; i += 256) hist[i] = 0;
    __syncthreads();
    for (int i = tid; i < cnt; i += 256)
        atomicAdd(&hist[bd[i] >> 17], 1);
    __syncthreads();
    // exclusive scan over PADDED lengths (4 per thread + block scan)
    int t4 = tid * 4;
    int a0 = hist[t4], a1 = hist[t4 + 1], a2 = hist[t4 + 2], a3 = hist[t4 + 3];
    int p0 = (a0 + 7) & ~7, p1 = (a1 + 7) & ~7, p2 = (a2 + 7) & ~7, p3 = (a3 + 7) & ~7;
    int ts = p0 + p1 + p2 + p3;
    ssum[tid] = ts;
    __syncthreads();
    #pragma unroll
    for (int off = 1; off < 256; off <<= 1) {
        int tmp = (tid >= off) ? ssum[tid - off] : 0;
        __syncthreads();
        ssum[tid] += tmp;
        __syncthreads();
    }
    int ex = ssum[tid] - ts;
    start[t4] = ex; start[t4 + 1] = ex + p0;
    start[t4 + 2] = ex + p0 + p1; start[t4 + 3] = ex + p0 + p1 + p2;
    __syncthreads();
    // CSR meta (packed) + convert hist -> cursors
    for (int i = tid; i < 1024; i += 256) {
        int bucket = (bin << 10) + i;
        if (bucket < MM)
            meta[bucket] = make_uint2((unsigned)(bin * BCAP_PAD + start[i]),
                                      (unsigned)hist[i]);
        hist[i] = start[i];
    }
    __syncthreads();
    int* sb = sorted + (size_t)bin * BCAP_PAD;
    // scatter srcs bucket-contiguous (writes confined to L2-resident window)
    for (int i = tid; i < cnt; i += 256) {
        int w = bd[i];
        int pos = atomicAdd(&hist[w >> 17], 1);
        if (pos < BCAP_PAD) sb[pos] = w & 0x1ffff;
    }
    __syncthreads();
    // pad fill: positions [start+d, start+padlen) get zero-row index NN
    for (int i = tid; i < 1024; i += 256) {
        int s0 = start[i];
        int d = hist[i] - s0;              // final cursor - start = raw count
        int pl = (d + 7) & ~7;
        for (int p = s0 + d; p < s0 + pl; ++p)
            if (p < BCAP_PAD) sb[p] = NN;
    }
}

// ---------------- gather-aggregate: 4 buckets per wave, shared latency rounds ------
__global__ __launch_bounds__(256) void aggregate_kernel(
    const ushort* __restrict__ xh, const int* __restrict__ sorted,
    const uint2* __restrict__ meta, ushort* __restrict__ aggh)
{
    int grp = blockIdx.x * 4 + (threadIdx.x >> 6);   // wave's group; grid exact: MM/16 blocks
    int lane = threadIdx.x & 63;
    int bid0 = grp * 4;                              // 4 consecutive buckets, same bin
    uint2 m = meta[bid0 + (lane & 3)];               // one load round for all 4 metas
    int st[4], dg[4];
    #pragma unroll
    for (int b = 0; b < 4; ++b) {
        st[b] = __builtin_amdgcn_readlane((int)m.x, b);
        dg[b] = __builtin_amdgcn_readlane((int)m.y, b);
    }
    int start0 = st[0];
    int L = (st[3] - start0) + ((dg[3] + 7) & ~7);   // combined padded length
    const unsigned* xu = (const unsigned*)xh;
    float ax[4], ay[4];
    #pragma unroll
    for (int b = 0; b < 4; ++b) { ax[b] = 0.f; ay[b] = 0.f; }

    if (L <= 64) {                                   // ~always (P(fail) ~ 2e-7)
        int sidx = sorted[start0 + lane];            // one preload covers all 4 buckets
        #pragma unroll
        for (int b = 0; b < 4; ++b) {
            int off = st[b] - start0;
            int degp = (dg[b] + 7) & ~7;
            for (int j = 0; j < degp; j += 8) {
                #pragma unroll
                for (int u = 0; u < 8; ++u) {
                    int sj = __builtin_amdgcn_readlane(sidx, off + j + u); // SGPR row idx
                    unsigned v = xu[(size_t)sj * 64 + lane];               // SGPR-base gather
                    ax[b] += bflo(v);
                    ay[b] += bfhi(v);
                }
            }
        }
    } else {                                         // rare fallback: uniform-addr loads
        #pragma unroll
        for (int b = 0; b < 4; ++b) {
            const int* sb = sorted + st[b];
            int degp = (dg[b] + 7) & ~7;
            for (int j = 0; j < degp; j += 8) {
                #pragma unroll
                for (int u = 0; u < 8; ++u) {
                    int sj = sb[j + u];              // padded: always valid
                    unsigned v = xu[(size_t)sj * 64 + lane];
                    ax[b] += bflo(v);
                    ay[b] += bfhi(v);
                }
            }
        }
    }
    #pragma unroll
    for (int b = 0; b < 4; ++b) {
        int deg = dg[b];
        float sc = 1.0f / (float)(deg > 1 ? deg : 1);
        unsigned o = (unsigned)f2bf(ax[b] * sc) | ((unsigned)f2bf(ay[b] * sc) << 16);
        ((unsigned*)(aggh + (size_t)(bid0 + b) * DD))[lane] = o;
    }
}

// ---------------- fused GEMM: out = relu([xh|agg]@QBt^T + cb) @ P2t^T + b2 ----------
// Stage1: 128x128 h-tile via 8 K-chunks (As/Bs in LDS). h -> LDS (bf16).
// Stage2: K=128 fully local: h_tile @ P2 -> out.
// LDS union: stage1 As[128][72]+Bs[128][72] = 36,864 B; stage2 Hs[128][136]+Ps[128][136]
// = 69,632 B  ->  S = 34,816 ushorts (69.6 KB, 2 blocks/CU).
__global__ __launch_bounds__(256) void gemm_fused_kernel(
    const ushort* __restrict__ xh, const ushort* __restrict__ aggh,
    const ushort* __restrict__ QBt, const float* __restrict__ cb,
    const ushort* __restrict__ P2t, const float* __restrict__ b2,
    float* __restrict__ out)
{
    __shared__ ushort S[34816];                        // 69,632 B
    ushort (*As)[72]  = (ushort(*)[72])S;              // stage1 A  [128][72]
    ushort (*Bs)[72]  = (ushort(*)[72])(S + 9216);     // stage1 B  [128][72]
    ushort (*Hs)[136] = (ushort(*)[136])S;             // stage2 A  [128][136]
    ushort (*Ps)[136] = (ushort(*)[136])(S + 17408);   // stage2 B  [128][136]

    int tid = threadIdx.x;
    int n0 = blockIdx.x * 128;
    int wid = tid >> 6;
    int lane = tid & 63;
    int wr = wid >> 1, wc = wid & 1;
    int lrow = lane & 15;
    int lk = (lane >> 4) * 8;

    f32x4 acc[4][4];
    #pragma unroll
    for (int i = 0; i < 4; ++i)
        #pragma unroll
        for (int j = 0; j < 4; ++j) acc[i][j] = (f32x4){0.f, 0.f, 0.f, 0.f};

    for (int c = 0; c < 8; ++c) {
        int seg = c >> 1;
        int kloc = (c & 1) * 64;
        const ushort* Abase = (seg == 0) ? xh : (aggh + (size_t)(seg - 1) * NN * DD);
        if (c) __syncthreads();
        #pragma unroll
        for (int i = 0; i < 4; ++i) {
            int id = tid + i * 256;
            int row = id >> 3;
            int s16 = id & 7;
            int grow = n0 + row;
            ushort8 v = {0, 0, 0, 0, 0, 0, 0, 0};
            if (grow < NN)
                v = *(const ushort8*)(Abase + (size_t)grow * DD + kloc + s16 * 8);
            *(ushort8*)&As[row][s16 * 8] = v;
        }
        #pragma unroll
        for (int i = 0; i < 4; ++i) {
            int id = tid + i * 256;
            int n = id >> 3;
            int s16 = id & 7;
            *(ushort8*)&Bs[n][s16 * 8] =
                *(const ushort8*)(QBt + (size_t)n * 512 + c * 64 + s16 * 8);
        }
        __syncthreads();
        #pragma unroll
        for (int ks = 0; ks < 2; ++ks) {
            bf16x8 a[4], b[4];
            #pragma unroll
            for (int mi = 0; mi < 4; ++mi)
                a[mi] = *(const bf16x8*)&As[wr * 64 + mi * 16 + lrow][ks * 32 + lk];
            #pragma unroll
            for (int ni = 0; ni < 4; ++ni)
                b[ni] = *(const bf16x8*)&Bs[wc * 64 + ni * 16 + lrow][ks * 32 + lk];
            #pragma unroll
            for (int mi = 0; mi < 4; ++mi)
                #pragma unroll
                for (int ni = 0; ni < 4; ++ni)
                    acc[mi][ni] = __builtin_amdgcn_mfma_f32_16x16x32_bf16(
                        a[mi], b[ni], acc[mi][ni], 0, 0, 0);
        }
    }

    __syncthreads();   // all stage1 LDS reads done before repurposing

    // epilogue1: h = relu(acc + cb) -> Hs (bf16); C/D layout row=(lane>>4)*4+q, col=lane&15
    int crow = lane >> 4;
    int ccol = lane & 15;
    #pragma unroll
    for (int ni = 0; ni < 4; ++ni) {
        int gcol = wc * 64 + ni * 16 + ccol;
        float cv = cb[gcol];
        #pragma unroll
        for (int mi = 0; mi < 4; ++mi) {
            #pragma unroll
            for (int q = 0; q < 4; ++q) {
                float v = acc[mi][ni][q] + cv;
                v = v > 0.f ? v : 0.f;
                Hs[wr * 64 + mi * 16 + crow * 4 + q][gcol] = f2bf(v);
            }
        }
    }
    // stage P2t: 128 rows x 128 k (16 ushort8 per row)
    #pragma unroll
    for (int i = 0; i < 8; ++i) {
        int id = tid + i * 256;
        int n = id >> 4, cc = id & 15;
        *(ushort8*)&Ps[n][cc * 8] = *(const ushort8*)(P2t + (size_t)n * DD + cc * 8);
    }
    __syncthreads();

    f32x4 acc2[4][4];
    #pragma unroll
    for (int i = 0; i < 4; ++i)
        #pragma unroll
        for (int j = 0; j < 4; ++j) acc2[i][j] = (f32x4){0.f, 0.f, 0.f, 0.f};

    #pragma unroll
    for (int ks = 0; ks < 4; ++ks) {
        bf16x8 a[4], b[4];
        #pragma unroll
        for (int mi = 0; mi < 4; ++mi)
            a[mi] = *(const bf16x8*)&Hs[wr * 64 + mi * 16 + lrow][ks * 32 + lk];
        #pragma unroll
        for (int ni = 0; ni < 4; ++ni)
            b[ni] = *(const bf16x8*)&Ps[wc * 64 + ni * 16 + lrow][ks * 32 + lk];
        #pragma unroll
        for (int mi = 0; mi < 4; ++mi)
            #pragma unroll
            for (int ni = 0; ni < 4; ++ni)
                acc2[mi][ni] = __builtin_amdgcn_mfma_f32_16x16x32_bf16(
                    a[mi], b[ni], acc2[mi][ni], 0, 0, 0);
    }

    #pragma unroll
    for (int ni = 0; ni < 4; ++ni) {
        int gcol = wc * 64 + ni * 16 + ccol;
        float bv = b2[gcol];
        #pragma unroll
        for (int mi = 0; mi < 4; ++mi) {
            #pragma unroll
            for (int q = 0; q < 4; ++q) {
                int gr = n0 + wr * 64 + mi * 16 + crow * 4 + q;
                if (gr < NN)
                    out[(size_t)gr * DD + gcol] = acc2[mi][ni][q] + bv;
            }
        }
    }
}

extern "C" void kernel_launch(void* const* d_in, const int* in_sizes, int n_in,
                              void* d_out, int out_size, void* d_ws, size_t ws_size,
                              hipStream_t stream) {
    const float* x  = (const float*)d_in[0];
    const int*   e0 = (const int*)d_in[1];
    const int*   e1 = (const int*)d_in[2];
    const int*   e2 = (const int*)d_in[3];
    const float* Wl = (const float*)d_in[4];
    const float* bl = (const float*)d_in[5];
    const float* Wr = (const float*)d_in[6];
    const float* P1 = (const float*)d_in[7];
    const float* b1 = (const float*)d_in[8];
    const float* P2 = (const float*)d_in[9];
    const float* b2 = (const float*)d_in[10];
    float* out = (float*)d_out;

    // ws layout (~124 MB)
    ushort* xh       = (ushort*)d_ws;                     // (N+1)*D    (25.6 MB; row N = zeros)
    ushort* aggh     = xh + (size_t)(NN + 1) * DD;        // R*N*D      (76.8 MB)
    ushort* QBt      = aggh + (size_t)RR * NN * DD;       // 128*512
    ushort* P2t      = QBt + (size_t)128 * 512;           // 128*128
    float*  cb       = (float*)(P2t + (size_t)DD * DD);   // D
    int*    g_cursor = (int*)(cb + DD);                   // NBIN
    int*    g_bindat = g_cursor + NBIN;                   // NBIN*BCAP_RAW (7.2 MB)
    int*    sorted   = g_bindat + (size_t)NBIN * BCAP_RAW;// NBIN*BCAP_PAD + 64 slack (12 MB)
    uint2*  meta     = (uint2*)(sorted + (size_t)NBIN * BCAP_PAD + 64);  // MM uint2

    hipMemsetAsync(g_cursor, 0, NBIN * sizeof(int), stream);
    hipMemsetAsync(xh + (size_t)NN * DD, 0, DD * sizeof(ushort), stream);  // zero row

    precompute_qbt_kernel<<<4 * DD, DD, 0, stream>>>(Wl, Wr, P1, QBt);
    precompute_p2t_kernel<<<DD, DD, 0, stream>>>(P2, P2t);
    precompute_c_kernel<<<1, DD, 0, stream>>>(bl, P1, b1, cb);

    x_tobf16_kernel<<<(NN * DD / 4 + 255) / 256, 256, 0, stream>>>(x, xh);

    int ablocks = (RR * EE + 4095) / 4096;   // 367
    bin_kernel<<<ablocks, 256, 0, stream>>>(e0, e1, e2, g_cursor, g_bindat);

    sort_kernel<<<NBIN, 256, 0, stream>>>(g_cursor, g_bindat, sorted, meta);

    aggregate_kernel<<<MM / 16, 256, 0, stream>>>(xh, sorted, meta, aggh);

    int gblocks = (NN + 127) / 128;
    gemm_fused_kernel<<<gblocks, 256, 0, stream>>>(xh, aggh, QBt, cb, P2t, b2, out);
}